// Round 5
// baseline (185.321 us; speedup 1.0000x reference)
//
#include <hip/hip_runtime.h>
#include <math.h>

#define TPB 256

typedef unsigned short u16;
typedef short bf16x8 __attribute__((ext_vector_type(8)));
typedef unsigned short u16x4 __attribute__((ext_vector_type(4)));
typedef float f32x4 __attribute__((ext_vector_type(4)));

__device__ __forceinline__ u16 f2bf(float x) {
    unsigned u = __float_as_uint(x);
    unsigned r = u + 0x7fffu + ((u >> 16) & 1u);
    return (u16)(r >> 16);
}
// storage permutation within a 32-wide k chunk; flag=1: half-split layout, flag=0: identity
__device__ __forceinline__ int pos32(int kk, int flag) {
    return flag ? (((kk >> 2) & 3) * 8 + (kk >> 4) * 4 + (kk & 3)) : kk;
}

// ---------------- probe: determine MFMA A/B fragment k-mapping on device; zero f_acc ----------------
__device__ __forceinline__ float probeA(int i, int k) { return (float)((i * 37 + k * 11) % 13 - 6); }
__device__ __forceinline__ float probeB(int k, int j) { return (float)((k * 7 + j * 29) % 11 - 5); }

__global__ void probe_kernel(int* flag, float* f_acc) {
    int l = threadIdx.x;
    int col = l & 15;
    float ref[4];
    #pragma unroll
    for (int j = 0; j < 4; ++j) {
        int row = 4 * (l >> 4) + j;
        float s = 0.f;
        for (int k = 0; k < 32; ++k) s += probeA(row, k) * probeB(k, col);
        ref[j] = s;
    }
    f32x4 z = {0.f, 0.f, 0.f, 0.f};
    bf16x8 a, b;
    #pragma unroll
    for (int i = 0; i < 8; ++i) {  // layout A: half-split
        int k = 4 * (l >> 4) + (i & 3) + 16 * (i >> 2);
        a[i] = (short)f2bf(probeA(l & 15, k));
        b[i] = (short)f2bf(probeB(k, l & 15));
    }
    f32x4 dA = __builtin_amdgcn_mfma_f32_16x16x32_bf16(a, b, z, 0, 0, 0);
    bool okA = dA[0] == ref[0] && dA[1] == ref[1] && dA[2] == ref[2] && dA[3] == ref[3];
    #pragma unroll
    for (int i = 0; i < 8; ++i) {  // layout B: consecutive 8
        int k = 8 * (l >> 4) + i;
        a[i] = (short)f2bf(probeA(l & 15, k));
        b[i] = (short)f2bf(probeB(k, l & 15));
    }
    f32x4 dB = __builtin_amdgcn_mfma_f32_16x16x32_bf16(a, b, z, 0, 0, 0);
    bool okB = dB[0] == ref[0] && dB[1] == ref[1] && dB[2] == ref[2] && dB[3] == ref[3];
    int allA = __all(okA), allB = __all(okB);
    if (l == 0) {
        *flag = allA ? 1 : (allB ? 0 : 1);
        f_acc[0] = 0.f;
    }
}

// ---------------- bias vectors r[i] = u_p[i]·w1, c[j] = u_c[j]·w2 ----------------
__global__ __launch_bounds__(TPB) void bias_kernel(
    const float* __restrict__ u_p, const float* __restrict__ u_c,
    const float* __restrict__ wa, float* __restrict__ r, float* __restrict__ c,
    int m, int n, int d) {
    int b = blockIdx.x;
    const float* src; const float* w; float* dst;
    if (b < m) { src = u_p + (size_t)b * d;       w = wa;     dst = r + b; }
    else       { src = u_c + (size_t)(b - m) * d; w = wa + d; dst = c + (b - m); }
    float acc = 0.f;
    for (int k4 = threadIdx.x; k4 < d / 4; k4 += TPB) {
        float4 a = ((const float4*)src)[k4];
        float4 ww = ((const float4*)w)[k4];
        acc += a.x * ww.x + a.y * ww.y + a.z * ww.z + a.w * ww.w;
    }
    __shared__ float red[TPB];
    red[threadIdx.x] = acc;
    __syncthreads();
    for (int s = TPB / 2; s > 0; s >>= 1) {
        if (threadIdx.x < s) red[threadIdx.x] += red[threadIdx.x + s];
        __syncthreads();
    }
    if (threadIdx.x == 0) *dst = red[0];
}

// ---------------- init S[i][j] = r[i] + c[j] ----------------
__global__ __launch_bounds__(TPB) void initS_kernel(
    const float* __restrict__ r, const float* __restrict__ c,
    float* __restrict__ S, int m, int n) {
    int q = blockIdx.x * TPB + threadIdx.x;
    int nq = n >> 2;
    if (q >= m * nq) return;
    int i = q / nq;
    int j = (q - i * nq) * 4;
    float ri = r[i];
    float4 cj = *(const float4*)(c + j);
    float4 o = {ri + cj.x, ri + cj.y, ri + cj.z, ri + cj.w};
    *(float4*)(S + (size_t)i * n + j) = o;
}

// ---------------- convert: upw3/uc -> bf16 (permuted k), W1eff/W3eff, term1 = sum(up*W0) ----------------
__global__ __launch_bounds__(TPB) void convert_kernel(
    const float* __restrict__ up, const float* __restrict__ uc,
    const float* __restrict__ wa, const float* __restrict__ W,
    u16* __restrict__ upw3, u16* __restrict__ ucb,
    float* __restrict__ W1eff, float* __restrict__ W3eff,
    float* __restrict__ f_acc,
    const int* __restrict__ flagp, int m, int n, int d) {
    int fl = *flagp;
    const float* w3 = wa + 2 * d;
    int dq = d / 4;
    int qup = m * dq;
    int qtot = (m + n) * dq;
    float acc1 = 0.f;
    for (int q = blockIdx.x * TPB + threadIdx.x; q < qtot; q += gridDim.x * TPB) {
        if (q < qup) {
            int row = q / dq;
            int k = (q - row * dq) * 4;
            float4 v = *(const float4*)(up + (size_t)row * d + k);
            float4 w = *(const float4*)(w3 + k);
            int p = (k & ~31) + pos32(k & 31, fl);
            u16x4 hi = {f2bf(v.x * w.x), f2bf(v.y * w.y), f2bf(v.z * w.z), f2bf(v.w * w.w)};
            *(u16x4*)(upw3 + (size_t)row * d + p) = hi;
            if (row < n) {
                const float* wr = W + (size_t)row * 4 * d;
                float4 w0 = *(const float4*)(wr + k);
                float4 w1 = *(const float4*)(wr + d + k);
                float4 w2 = *(const float4*)(wr + 2 * d + k);
                float4 e;
                e.x = w1.x + v.x * w2.x; e.y = w1.y + v.y * w2.y;
                e.z = w1.z + v.z * w2.z; e.w = w1.w + v.w * w2.w;
                *(float4*)(W1eff + (size_t)row * d + k) = e;
                acc1 += v.x * w0.x + v.y * w0.y + v.z * w0.z + v.w * w0.w;
            }
        } else {
            int q2 = q - qup;
            int row = q2 / dq;
            int k = (q2 - row * dq) * 4;
            float4 v = *(const float4*)(uc + (size_t)row * d + k);
            int p = (k & ~31) + pos32(k & 31, fl);
            u16x4 hi = {f2bf(v.x), f2bf(v.y), f2bf(v.z), f2bf(v.w)};
            *(u16x4*)(ucb + (size_t)row * d + p) = hi;
            const float* wr = W + (size_t)row * 4 * d;
            float4 w3r = *(const float4*)(wr + 3 * d + k);
            float4 e = {v.x * w3r.x, v.y * w3r.y, v.z * w3r.z, v.w * w3r.w};
            *(float4*)(W3eff + (size_t)row * d + k) = e;
        }
    }
    __shared__ float red[TPB];
    red[threadIdx.x] = acc1;
    __syncthreads();
    for (int s = TPB / 2; s > 0; s >>= 1) {
        if (threadIdx.x < s) red[threadIdx.x] += red[threadIdx.x + s];
        __syncthreads();
    }
    if (threadIdx.x == 0) unsafeAtomicAdd(f_acc, red[0]);
}

// ---------------- transpose: src[rows][d] f32 -> dst[d][rows] bf16, perm on row index ----------------
__global__ __launch_bounds__(TPB) void transpose_kernel(
    const float* __restrict__ src, u16* __restrict__ dst,
    const int* __restrict__ flagp, int rows, int d) {
    __shared__ float t[64 * 65];
    int fl = *flagp;
    int tid = threadIdx.x;
    int r0 = blockIdx.y * 64;
    int c0 = blockIdx.x * 64;
    #pragma unroll
    for (int it = 0; it < 4; ++it) {
        int rr = (tid >> 4) + it * 16;
        int cc = (tid & 15) * 4;
        float4 v = *(const float4*)(src + (size_t)(r0 + rr) * d + c0 + cc);
        t[(cc + 0) * 65 + rr] = v.x;
        t[(cc + 1) * 65 + rr] = v.y;
        t[(cc + 2) * 65 + rr] = v.z;
        t[(cc + 3) * 65 + rr] = v.w;
    }
    __syncthreads();
    #pragma unroll
    for (int it = 0; it < 2; ++it) {
        int id = tid + it * TPB;
        int kc = id >> 3;
        int s = id & 7;
        u16 outv[8];
        #pragma unroll
        for (int e = 0; e < 8; ++e) {
            int p = s * 8 + e;
            int jloc;
            if (fl) {
                int p5 = p & 31;
                jloc = 32 * (p >> 5) + 16 * ((p5 >> 2) & 1) + 4 * (p5 >> 3) + (p5 & 3);
            } else jloc = p;
            outv[e] = f2bf(t[kc * 65 + jloc]);
        }
        *(u16x4*)(dst + (size_t)(c0 + kc) * rows + r0 + s * 8) = *(u16x4*)&outv[0];
        *(u16x4*)(dst + (size_t)(c0 + kc) * rows + r0 + s * 8 + 4) = *(u16x4*)&outv[4];
    }
}

// ---------------- MFMA GEMM: S += upw3 @ uc^T, split-K over blockIdx.z, single bf16 ----------------
__global__ __launch_bounds__(TPB) void gemmS_mfma(
    const u16* __restrict__ Ah, const u16* __restrict__ Bh,
    float* __restrict__ S, int n, int d, int ksplit) {
    __shared__ u16 sAh[4096];
    __shared__ u16 sBh[4096];
    int tid = threadIdx.x;
    int lane = tid & 63, wave = tid >> 6;
    int wm = wave >> 1, wn = wave & 1;
    int lrow = lane & 15, g = lane >> 4;
    int i0 = blockIdx.y * 64, j0 = blockIdx.x * 64;
    int kchunk = d / ksplit;
    int kbeg = blockIdx.z * kchunk;
    f32x4 acc[2][2];
    #pragma unroll
    for (int a = 0; a < 2; ++a)
        #pragma unroll
        for (int b = 0; b < 2; ++b) acc[a][b] = (f32x4){0.f, 0.f, 0.f, 0.f};

    for (int k0 = kbeg; k0 < kbeg + kchunk; k0 += 64) {
        #pragma unroll
        for (int it = 0; it < 2; ++it) {
            int id = tid + it * TPB;
            int row = id >> 3, slot = id & 7;
            int boff = (row * 128 + slot * 16) ^ ((row & 7) << 4);
            *(int4*)((char*)sAh + boff) = *(const int4*)(Ah + (size_t)(i0 + row) * d + k0 + slot * 8);
            *(int4*)((char*)sBh + boff) = *(const int4*)(Bh + (size_t)(j0 + row) * d + k0 + slot * 8);
        }
        __syncthreads();
        #pragma unroll
        for (int kk = 0; kk < 2; ++kk) {
            bf16x8 afh[2], bfh[2];
            #pragma unroll
            for (int mr = 0; mr < 2; ++mr) {
                int row = wm * 32 + mr * 16 + lrow;
                int boff = (row * 128 + kk * 64 + g * 16) ^ ((row & 7) << 4);
                afh[mr] = *(const bf16x8*)((const char*)sAh + boff);
            }
            #pragma unroll
            for (int nr = 0; nr < 2; ++nr) {
                int row = wn * 32 + nr * 16 + lrow;
                int boff = (row * 128 + kk * 64 + g * 16) ^ ((row & 7) << 4);
                bfh[nr] = *(const bf16x8*)((const char*)sBh + boff);
            }
            #pragma unroll
            for (int mr = 0; mr < 2; ++mr)
                #pragma unroll
                for (int nr = 0; nr < 2; ++nr)
                    acc[mr][nr] = __builtin_amdgcn_mfma_f32_16x16x32_bf16(afh[mr], bfh[nr], acc[mr][nr], 0, 0, 0);
        }
        __syncthreads();
    }
    int crow = (lane >> 4) * 4;
    int ccol = lane & 15;
    #pragma unroll
    for (int mr = 0; mr < 2; ++mr) {
        #pragma unroll
        for (int nr = 0; nr < 2; ++nr) {
            int jc = j0 + wn * 32 + nr * 16 + ccol;
            #pragma unroll
            for (int jr = 0; jr < 4; ++jr) {
                int i = i0 + wm * 32 + mr * 16 + crow + jr;
                unsafeAtomicAdd(&S[(size_t)i * n + jc], acc[mr][nr][jr]);
            }
        }
    }
}

// ---------------- row softmax stats ----------------
__global__ __launch_bounds__(TPB) void row_stats_kernel(
    const float* __restrict__ S, float* __restrict__ rm, float* __restrict__ inv_rs, int n) {
    int row = blockIdx.x;
    const float* p = S + (size_t)row * n;
    float v[8];
    int cnt = 0;
    float mx = -INFINITY;
    for (int t = threadIdx.x; t < n; t += TPB) {
        v[cnt] = p[t];
        mx = fmaxf(mx, v[cnt]);
        ++cnt;
    }
    __shared__ float red[TPB];
    red[threadIdx.x] = mx;
    __syncthreads();
    for (int s = TPB / 2; s > 0; s >>= 1) {
        if (threadIdx.x < s) red[threadIdx.x] = fmaxf(red[threadIdx.x], red[threadIdx.x + s]);
        __syncthreads();
    }
    float gm = red[0];
    __syncthreads();
    float sum = 0.f;
    for (int u = 0; u < cnt; ++u) sum += __expf(v[u] - gm);
    red[threadIdx.x] = sum;
    __syncthreads();
    for (int s = TPB / 2; s > 0; s >>= 1) {
        if (threadIdx.x < s) red[threadIdx.x] += red[threadIdx.x + s];
        __syncthreads();
    }
    if (threadIdx.x == 0) { rm[row] = gm; inv_rs[row] = 1.f / red[0]; }
}

// ---------------- column softmax stats ----------------
__global__ __launch_bounds__(TPB) void col_stats_partial(
    const float* __restrict__ S, float* __restrict__ pm, float* __restrict__ ps,
    int n, int rows_per) {
    int col = blockIdx.x * TPB + threadIdx.x;
    int r0 = blockIdx.y * rows_per;
    float mx = -INFINITY, s = 0.f;
    for (int i = 0; i < rows_per; ++i) {
        float v = S[(size_t)(r0 + i) * n + col];
        if (v <= mx) {
            s += __expf(v - mx);
        } else {
            s = s * __expf(mx - v) + 1.f;
            mx = v;
        }
    }
    pm[(size_t)blockIdx.y * n + col] = mx;
    ps[(size_t)blockIdx.y * n + col] = s;
}

__global__ __launch_bounds__(TPB) void col_stats_merge(
    const float* __restrict__ pm, const float* __restrict__ ps,
    float* __restrict__ cm, float* __restrict__ inv_cs, int n, int chunks) {
    int col = blockIdx.x * TPB + threadIdx.x;
    float mx = -INFINITY;
    for (int c = 0; c < chunks; ++c) mx = fmaxf(mx, pm[(size_t)c * n + col]);
    float s = 0.f;
    for (int c = 0; c < chunks; ++c) s += ps[(size_t)c * n + col] * __expf(pm[(size_t)c * n + col] - mx);
    cm[col] = mx;
    inv_cs[col] = 1.f / s;
}

// ---------------- MFMA GEMM + fused dot: term2 = sum_{i,kc} aa_part[i,kc] * W1eff[i,kc] ----------------
__global__ __launch_bounds__(TPB) void aalpha_mfma(
    const float* __restrict__ S, const float* __restrict__ rm, const float* __restrict__ irs,
    const u16* __restrict__ ucT, const float* __restrict__ W1eff, float* __restrict__ f_acc,
    const int* __restrict__ flagp, int m, int n, int d, int jsplit) {
    __shared__ u16 sA[4096];
    __shared__ u16 sB[4096];
    __shared__ float redf[TPB];
    int fl = *flagp;
    int tid = threadIdx.x;
    int lane = tid & 63, wave = tid >> 6;
    int wm = wave >> 1, wn = wave & 1;
    int lrow = lane & 15, g = lane >> 4;
    int i0 = blockIdx.y * 64, kc0 = blockIdx.x * 64;
    int jchunk = n / jsplit;
    int jbeg = blockIdx.z * jchunk;
    f32x4 acc[2][2];
    #pragma unroll
    for (int a = 0; a < 2; ++a)
        #pragma unroll
        for (int b = 0; b < 2; ++b) acc[a][b] = (f32x4){0.f, 0.f, 0.f, 0.f};

    for (int j0 = jbeg; j0 < jbeg + jchunk; j0 += 64) {
        #pragma unroll
        for (int it = 0; it < 4; ++it) {
            int id = tid + it * TPB;
            int row = id >> 4;
            int cq = id & 15;
            float4 sv = *(const float4*)(S + (size_t)(i0 + row) * n + j0 + cq * 4);
            float mi = rm[i0 + row], sc = irs[i0 + row];
            int p = fl ? (32 * (cq >> 3) + (cq & 3) * 8 + ((cq >> 2) & 1) * 4) : cq * 4;
            int boff = (row * 128 + p * 2) ^ ((row & 7) << 4);
            u16x4 pv = {f2bf(__expf(sv.x - mi) * sc), f2bf(__expf(sv.y - mi) * sc),
                        f2bf(__expf(sv.z - mi) * sc), f2bf(__expf(sv.w - mi) * sc)};
            *(u16x4*)((char*)sA + boff) = pv;
        }
        #pragma unroll
        for (int it = 0; it < 2; ++it) {
            int id = tid + it * TPB;
            int row = id >> 3, slot = id & 7;
            int boff = (row * 128 + slot * 16) ^ ((row & 7) << 4);
            *(int4*)((char*)sB + boff) = *(const int4*)(ucT + (size_t)(kc0 + row) * n + j0 + slot * 8);
        }
        __syncthreads();
        #pragma unroll
        for (int kk = 0; kk < 2; ++kk) {
            bf16x8 av[2], bv[2];
            #pragma unroll
            for (int mr = 0; mr < 2; ++mr) {
                int row = wm * 32 + mr * 16 + lrow;
                int boff = (row * 128 + kk * 64 + g * 16) ^ ((row & 7) << 4);
                av[mr] = *(const bf16x8*)((const char*)sA + boff);
            }
            #pragma unroll
            for (int nr = 0; nr < 2; ++nr) {
                int row = wn * 32 + nr * 16 + lrow;
                int boff = (row * 128 + kk * 64 + g * 16) ^ ((row & 7) << 4);
                bv[nr] = *(const bf16x8*)((const char*)sB + boff);
            }
            #pragma unroll
            for (int mr = 0; mr < 2; ++mr)
                #pragma unroll
                for (int nr = 0; nr < 2; ++nr)
                    acc[mr][nr] = __builtin_amdgcn_mfma_f32_16x16x32_bf16(av[mr], bv[nr], acc[mr][nr], 0, 0, 0);
        }
        __syncthreads();
    }
    int crow = (lane >> 4) * 4;
    int ccol = lane & 15;
    float t2 = 0.f;
    #pragma unroll
    for (int mr = 0; mr < 2; ++mr)
        #pragma unroll
        for (int nr = 0; nr < 2; ++nr) {
            int kc = kc0 + wn * 32 + nr * 16 + ccol;
            #pragma unroll
            for (int jr = 0; jr < 4; ++jr) {
                int i = i0 + wm * 32 + mr * 16 + crow + jr;
                if (i < n) t2 += acc[mr][nr][jr] * W1eff[(size_t)i * d + kc];
            }
        }
    redf[tid] = t2;
    __syncthreads();
    for (int s = TPB / 2; s > 0; s >>= 1) {
        if (tid < s) redf[tid] += redf[tid + s];
        __syncthreads();
    }
    if (tid == 0) unsafeAtomicAdd(f_acc, redf[0]);
}

// ---------------- MFMA GEMM + fused dot: term3 = sum_{j,kc} ab_part[j,kc] * W3eff[j,kc] ----------------
__global__ __launch_bounds__(TPB) void abeta_mfma(
    const float* __restrict__ S, const float* __restrict__ cm, const float* __restrict__ ics,
    const u16* __restrict__ upT, const float* __restrict__ W3eff, float* __restrict__ f_acc,
    const int* __restrict__ flagp, int m, int n, int d, int isplit) {
    __shared__ u16 sA[4096];
    __shared__ u16 sB[4096];
    __shared__ float redf[TPB];
    int fl = *flagp;
    int tid = threadIdx.x;
    int lane = tid & 63, wave = tid >> 6;
    int wm = wave >> 1, wn = wave & 1;
    int lrow = lane & 15, g = lane >> 4;
    int jb0 = blockIdx.y * 64, kc0 = blockIdx.x * 64;
    int ichunk = m / isplit;
    int ibeg = blockIdx.z * ichunk;
    f32x4 acc[2][2];
    #pragma unroll
    for (int a = 0; a < 2; ++a)
        #pragma unroll
        for (int b = 0; b < 2; ++b) acc[a][b] = (f32x4){0.f, 0.f, 0.f, 0.f};

    for (int i0 = ibeg; i0 < ibeg + ichunk; i0 += 64) {
        #pragma unroll
        for (int it = 0; it < 4; ++it) {
            int id = tid + it * TPB;
            int r = id >> 4;
            int cq = id & 15;
            float4 sv = *(const float4*)(S + (size_t)(i0 + r) * n + jb0 + cq * 4);
            float4 mj = *(const float4*)(cm + jb0 + cq * 4);
            float4 sj = *(const float4*)(ics + jb0 + cq * 4);
            int pi;
            if (fl) { int r5 = r & 31; pi = 32 * (r >> 5) + ((r5 >> 2) & 3) * 8 + (r5 >> 4) * 4 + (r5 & 3); }
            else pi = r;
            u16 v0 = f2bf(__expf(sv.x - mj.x) * sj.x);
            u16 v1 = f2bf(__expf(sv.y - mj.y) * sj.y);
            u16 v2 = f2bf(__expf(sv.z - mj.z) * sj.z);
            u16 v3 = f2bf(__expf(sv.w - mj.w) * sj.w);
            int j = cq * 4;
            *(u16*)((char*)sA + ((((j + 0) * 128) + pi * 2) ^ (((j + 0) & 7) << 4))) = v0;
            *(u16*)((char*)sA + ((((j + 1) * 128) + pi * 2) ^ (((j + 1) & 7) << 4))) = v1;
            *(u16*)((char*)sA + ((((j + 2) * 128) + pi * 2) ^ (((j + 2) & 7) << 4))) = v2;
            *(u16*)((char*)sA + ((((j + 3) * 128) + pi * 2) ^ (((j + 3) & 7) << 4))) = v3;
        }
        #pragma unroll
        for (int it = 0; it < 2; ++it) {
            int id = tid + it * TPB;
            int row = id >> 3, slot = id & 7;
            int boff = (row * 128 + slot * 16) ^ ((row & 7) << 4);
            *(int4*)((char*)sB + boff) = *(const int4*)(upT + (size_t)(kc0 + row) * m + i0 + slot * 8);
        }
        __syncthreads();
        #pragma unroll
        for (int kk = 0; kk < 2; ++kk) {
            bf16x8 av[2], bv[2];
            #pragma unroll
            for (int mr = 0; mr < 2; ++mr) {
                int row = wm * 32 + mr * 16 + lrow;
                int boff = (row * 128 + kk * 64 + g * 16) ^ ((row & 7) << 4);
                av[mr] = *(const bf16x8*)((const char*)sA + boff);
            }
            #pragma unroll
            for (int nr = 0; nr < 2; ++nr) {
                int row = wn * 32 + nr * 16 + lrow;
                int boff = (row * 128 + kk * 64 + g * 16) ^ ((row & 7) << 4);
                bv[nr] = *(const bf16x8*)((const char*)sB + boff);
            }
            #pragma unroll
            for (int mr = 0; mr < 2; ++mr)
                #pragma unroll
                for (int nr = 0; nr < 2; ++nr)
                    acc[mr][nr] = __builtin_amdgcn_mfma_f32_16x16x32_bf16(av[mr], bv[nr], acc[mr][nr], 0, 0, 0);
        }
        __syncthreads();
    }
    int crow = (lane >> 4) * 4;
    int ccol = lane & 15;
    float t3 = 0.f;
    #pragma unroll
    for (int mr = 0; mr < 2; ++mr)
        #pragma unroll
        for (int nr = 0; nr < 2; ++nr) {
            int kc = kc0 + wn * 32 + nr * 16 + ccol;
            #pragma unroll
            for (int jr = 0; jr < 4; ++jr) {
                int j = jb0 + wm * 32 + mr * 16 + crow + jr;
                t3 += acc[mr][nr][jr] * W3eff[(size_t)j * d + kc];
            }
        }
    redf[tid] = t3;
    __syncthreads();
    for (int s = TPB / 2; s > 0; s >>= 1) {
        if (tid < s) redf[tid] += redf[tid + s];
        __syncthreads();
    }
    if (tid == 0) unsafeAtomicAdd(f_acc, redf[0]);
}

// ---------------- final: out = relu(f_acc + bias) ----------------
__global__ void final_out(const float* __restrict__ f_acc, const float* __restrict__ bias,
                          float* __restrict__ out) {
    if (threadIdx.x == 0) {
        float v = f_acc[0] + bias[0];
        out[0] = v > 0.f ? v : 0.f;
    }
}

extern "C" void kernel_launch(void* const* d_in, const int* in_sizes, int n_in,
                              void* d_out, int out_size, void* d_ws, size_t ws_size,
                              hipStream_t stream) {
    const float* u_p = (const float*)d_in[0];
    const float* u_c = (const float*)d_in[1];
    const float* w_a = (const float*)d_in[2];
    const float* ffn_w = (const float*)d_in[3];
    const float* ffn_b = (const float*)d_in[4];
    float* out = (float*)d_out;

    int d = in_sizes[2] / 3;   // 2048
    int m = in_sizes[0] / d;   // 1024
    int n = in_sizes[1] / d;   // 1024
    const int CHUNKS = 64;
    const int KSPLIT = 4;      // gemmS:   1024 blocks = 4/CU
    const int JSPLIT = 2;      // aalpha:  1024 blocks = 4/CU
    const int ISPLIT = 2;      // abeta:   1024 blocks = 4/CU

    size_t md = (size_t)m * d, nd = (size_t)n * d, mn = (size_t)m * n;

    float* ws = (float*)d_ws;
    float* r = ws;                      // m
    float* c = r + m;                   // n
    float* rm = c + n;                  // m
    float* inv_rs = rm + m;             // m
    float* cm = inv_rs + m;             // n
    float* inv_cs = cm + n;             // n
    float* pm = inv_cs + n;             // CHUNKS*n
    float* ps = pm + (size_t)CHUNKS * n;
    float* f_acc = ps + (size_t)CHUNKS * n;     // 16 floats (pad)
    int* flagp = (int*)(f_acc + 16);            // 16 ints
    float* S = (float*)(flagp + 16);            // mn
    float* W1eff = S + mn;                      // md
    float* W3eff = W1eff + md;                  // nd
    u16* upw3 = (u16*)(W3eff + nd);             // md
    u16* ucb = upw3 + md;                       // nd
    u16* ucT = ucb + nd;                        // nd
    u16* upT = ucT + nd;                        // md

    probe_kernel<<<1, 64, 0, stream>>>(flagp, f_acc);
    bias_kernel<<<m + n, TPB, 0, stream>>>(u_p, u_c, w_a, r, c, m, n, d);
    convert_kernel<<<2048, TPB, 0, stream>>>(u_p, u_c, w_a, ffn_w, upw3, ucb,
                                             W1eff, W3eff, f_acc, flagp, m, n, d);
    dim3 gtc(d / 64, n / 64);
    transpose_kernel<<<gtc, TPB, 0, stream>>>(u_c, ucT, flagp, n, d);
    dim3 gtp(d / 64, m / 64);
    transpose_kernel<<<gtp, TPB, 0, stream>>>(u_p, upT, flagp, m, d);

    initS_kernel<<<(m * (n / 4) + TPB - 1) / TPB, TPB, 0, stream>>>(r, c, S, m, n);

    dim3 gS(n / 64, m / 64, KSPLIT);
    gemmS_mfma<<<gS, TPB, 0, stream>>>(upw3, ucb, S, n, d, KSPLIT);

    row_stats_kernel<<<m, TPB, 0, stream>>>(S, rm, inv_rs, n);
    dim3 gCP(n / TPB, CHUNKS);
    col_stats_partial<<<gCP, TPB, 0, stream>>>(S, pm, ps, n, m / CHUNKS);
    col_stats_merge<<<n / TPB, TPB, 0, stream>>>(pm, ps, cm, inv_cs, n, CHUNKS);

    dim3 gA(d / 64, m / 64, JSPLIT);
    aalpha_mfma<<<gA, TPB, 0, stream>>>(S, rm, inv_rs, ucT, W1eff, f_acc, flagp, m, n, d, JSPLIT);
    dim3 gB(d / 64, n / 64, ISPLIT);
    abeta_mfma<<<gB, TPB, 0, stream>>>(S, cm, inv_cs, upT, W3eff, f_acc, flagp, m, n, d, ISPLIT);

    final_out<<<1, 64, 0, stream>>>(f_acc, ffn_b, out);

    (void)out_size; (void)ws_size; (void)n_in;
}

// Round 6
// 169.672 us; speedup vs baseline: 1.0922x; 1.0922x over previous
//
#include <hip/hip_runtime.h>
#include <math.h>

#define TPB 256

typedef unsigned short u16;
typedef short bf16x8 __attribute__((ext_vector_type(8)));
typedef unsigned short u16x4 __attribute__((ext_vector_type(4)));
typedef float f32x4 __attribute__((ext_vector_type(4)));

__device__ __forceinline__ u16 f2bf(float x) {
    unsigned u = __float_as_uint(x);
    unsigned r = u + 0x7fffu + ((u >> 16) & 1u);
    return (u16)(r >> 16);
}
// storage permutation within a 32-wide k chunk; flag=1: half-split layout, flag=0: identity
__device__ __forceinline__ int pos32(int kk, int flag) {
    return flag ? (((kk >> 2) & 3) * 8 + (kk >> 4) * 4 + (kk & 3)) : kk;
}

// ---------------- probe: determine MFMA A/B fragment k-mapping on device ----------------
__device__ __forceinline__ float probeA(int i, int k) { return (float)((i * 37 + k * 11) % 13 - 6); }
__device__ __forceinline__ float probeB(int k, int j) { return (float)((k * 7 + j * 29) % 11 - 5); }

__global__ void probe_kernel(int* flag) {
    int l = threadIdx.x;
    int col = l & 15;
    float ref[4];
    #pragma unroll
    for (int j = 0; j < 4; ++j) {
        int row = 4 * (l >> 4) + j;
        float s = 0.f;
        for (int k = 0; k < 32; ++k) s += probeA(row, k) * probeB(k, col);
        ref[j] = s;
    }
    f32x4 z = {0.f, 0.f, 0.f, 0.f};
    bf16x8 a, b;
    #pragma unroll
    for (int i = 0; i < 8; ++i) {  // layout A: half-split
        int k = 4 * (l >> 4) + (i & 3) + 16 * (i >> 2);
        a[i] = (short)f2bf(probeA(l & 15, k));
        b[i] = (short)f2bf(probeB(k, l & 15));
    }
    f32x4 dA = __builtin_amdgcn_mfma_f32_16x16x32_bf16(a, b, z, 0, 0, 0);
    bool okA = dA[0] == ref[0] && dA[1] == ref[1] && dA[2] == ref[2] && dA[3] == ref[3];
    #pragma unroll
    for (int i = 0; i < 8; ++i) {  // layout B: consecutive 8
        int k = 8 * (l >> 4) + i;
        a[i] = (short)f2bf(probeA(l & 15, k));
        b[i] = (short)f2bf(probeB(k, l & 15));
    }
    f32x4 dB = __builtin_amdgcn_mfma_f32_16x16x32_bf16(a, b, z, 0, 0, 0);
    bool okB = dB[0] == ref[0] && dB[1] == ref[1] && dB[2] == ref[2] && dB[3] == ref[3];
    int allA = __all(okA), allB = __all(okB);
    if (l == 0) *flag = allA ? 1 : (allB ? 0 : 1);
}

// ---------------- bias vectors r[i] = u_p[i]·w1, c[j] = u_c[j]·w2 ----------------
__global__ __launch_bounds__(TPB) void bias_kernel(
    const float* __restrict__ u_p, const float* __restrict__ u_c,
    const float* __restrict__ wa, float* __restrict__ r, float* __restrict__ c,
    int m, int n, int d) {
    int b = blockIdx.x;
    const float* src; const float* w; float* dst;
    if (b < m) { src = u_p + (size_t)b * d;       w = wa;     dst = r + b; }
    else       { src = u_c + (size_t)(b - m) * d; w = wa + d; dst = c + (b - m); }
    float acc = 0.f;
    for (int k4 = threadIdx.x; k4 < d / 4; k4 += TPB) {
        float4 a = ((const float4*)src)[k4];
        float4 ww = ((const float4*)w)[k4];
        acc += a.x * ww.x + a.y * ww.y + a.z * ww.z + a.w * ww.w;
    }
    __shared__ float red[TPB];
    red[threadIdx.x] = acc;
    __syncthreads();
    for (int s = TPB / 2; s > 0; s >>= 1) {
        if (threadIdx.x < s) red[threadIdx.x] += red[threadIdx.x + s];
        __syncthreads();
    }
    if (threadIdx.x == 0) *dst = red[0];
}

// ---------------- init S[i][j] = r[i] + c[j] ----------------
__global__ __launch_bounds__(TPB) void initS_kernel(
    const float* __restrict__ r, const float* __restrict__ c,
    float* __restrict__ S, int m, int n) {
    int q = blockIdx.x * TPB + threadIdx.x;
    int nq = n >> 2;
    if (q >= m * nq) return;
    int i = q / nq;
    int j = (q - i * nq) * 4;
    float ri = r[i];
    float4 cj = *(const float4*)(c + j);
    float4 o = {ri + cj.x, ri + cj.y, ri + cj.z, ri + cj.w};
    *(float4*)(S + (size_t)i * n + j) = o;
}

// ---------------- pre-convert: upw3 = u_p*w3, uc -> bf16, permuted k layout ----------------
__global__ __launch_bounds__(TPB) void convert_kernel(
    const float* __restrict__ up, const float* __restrict__ uc,
    const float* __restrict__ wa,
    u16* __restrict__ upw3, u16* __restrict__ ucb,
    const int* __restrict__ flagp, int m, int n, int d) {
    int fl = *flagp;
    const float* w3 = wa + 2 * d;
    int dq = d / 4;
    int qup = m * dq;
    int qtot = (m + n) * dq;
    for (int q = blockIdx.x * TPB + threadIdx.x; q < qtot; q += gridDim.x * TPB) {
        if (q < qup) {
            int row = q / dq;
            int k = (q - row * dq) * 4;
            float4 v = *(const float4*)(up + (size_t)row * d + k);
            float4 w = *(const float4*)(w3 + k);
            int p = (k & ~31) + pos32(k & 31, fl);
            u16x4 hi = {f2bf(v.x * w.x), f2bf(v.y * w.y), f2bf(v.z * w.z), f2bf(v.w * w.w)};
            *(u16x4*)(upw3 + (size_t)row * d + p) = hi;
        } else {
            int q2 = q - qup;
            int row = q2 / dq;
            int k = (q2 - row * dq) * 4;
            float4 v = *(const float4*)(uc + (size_t)row * d + k);
            int p = (k & ~31) + pos32(k & 31, fl);
            u16x4 hi = {f2bf(v.x), f2bf(v.y), f2bf(v.z), f2bf(v.w)};
            *(u16x4*)(ucb + (size_t)row * d + p) = hi;
        }
    }
}

// ---------------- transpose: src[rows][d] f32 -> dst[d][rows] bf16, perm on row index ----------------
__global__ __launch_bounds__(TPB) void transpose_kernel(
    const float* __restrict__ src, u16* __restrict__ dst,
    const int* __restrict__ flagp, int rows, int d) {
    __shared__ float t[64 * 65];
    int fl = *flagp;
    int tid = threadIdx.x;
    int r0 = blockIdx.y * 64;
    int c0 = blockIdx.x * 64;
    #pragma unroll
    for (int it = 0; it < 4; ++it) {
        int rr = (tid >> 4) + it * 16;
        int cc = (tid & 15) * 4;
        float4 v = *(const float4*)(src + (size_t)(r0 + rr) * d + c0 + cc);
        t[(cc + 0) * 65 + rr] = v.x;
        t[(cc + 1) * 65 + rr] = v.y;
        t[(cc + 2) * 65 + rr] = v.z;
        t[(cc + 3) * 65 + rr] = v.w;
    }
    __syncthreads();
    #pragma unroll
    for (int it = 0; it < 2; ++it) {
        int id = tid + it * TPB;
        int kc = id >> 3;
        int s = id & 7;
        u16 outv[8];
        #pragma unroll
        for (int e = 0; e < 8; ++e) {
            int p = s * 8 + e;
            int jloc;
            if (fl) {
                int p5 = p & 31;
                jloc = 32 * (p >> 5) + 16 * ((p5 >> 2) & 1) + 4 * (p5 >> 3) + (p5 & 3);
            } else jloc = p;
            outv[e] = f2bf(t[kc * 65 + jloc]);
        }
        *(u16x4*)(dst + (size_t)(c0 + kc) * rows + r0 + s * 8) = *(u16x4*)&outv[0];
        *(u16x4*)(dst + (size_t)(c0 + kc) * rows + r0 + s * 8 + 4) = *(u16x4*)&outv[4];
    }
}

// ---------------- MFMA GEMM: S += upw3 @ uc^T, split-K over blockIdx.z, single bf16 ----------------
__global__ __launch_bounds__(TPB) void gemmS_mfma(
    const u16* __restrict__ Ah, const u16* __restrict__ Bh,
    float* __restrict__ S, int n, int d, int ksplit) {
    __shared__ u16 sAh[4096];
    __shared__ u16 sBh[4096];
    int tid = threadIdx.x;
    int lane = tid & 63, wave = tid >> 6;
    int wm = wave >> 1, wn = wave & 1;
    int lrow = lane & 15, g = lane >> 4;
    int i0 = blockIdx.y * 64, j0 = blockIdx.x * 64;
    int kchunk = d / ksplit;
    int kbeg = blockIdx.z * kchunk;
    f32x4 acc[2][2];
    #pragma unroll
    for (int a = 0; a < 2; ++a)
        #pragma unroll
        for (int b = 0; b < 2; ++b) acc[a][b] = (f32x4){0.f, 0.f, 0.f, 0.f};

    for (int k0 = kbeg; k0 < kbeg + kchunk; k0 += 64) {
        #pragma unroll
        for (int it = 0; it < 2; ++it) {
            int id = tid + it * TPB;
            int row = id >> 3, slot = id & 7;
            int boff = (row * 128 + slot * 16) ^ ((row & 7) << 4);
            *(int4*)((char*)sAh + boff) = *(const int4*)(Ah + (size_t)(i0 + row) * d + k0 + slot * 8);
            *(int4*)((char*)sBh + boff) = *(const int4*)(Bh + (size_t)(j0 + row) * d + k0 + slot * 8);
        }
        __syncthreads();
        #pragma unroll
        for (int kk = 0; kk < 2; ++kk) {
            bf16x8 afh[2], bfh[2];
            #pragma unroll
            for (int mr = 0; mr < 2; ++mr) {
                int row = wm * 32 + mr * 16 + lrow;
                int boff = (row * 128 + kk * 64 + g * 16) ^ ((row & 7) << 4);
                afh[mr] = *(const bf16x8*)((const char*)sAh + boff);
            }
            #pragma unroll
            for (int nr = 0; nr < 2; ++nr) {
                int row = wn * 32 + nr * 16 + lrow;
                int boff = (row * 128 + kk * 64 + g * 16) ^ ((row & 7) << 4);
                bfh[nr] = *(const bf16x8*)((const char*)sBh + boff);
            }
            #pragma unroll
            for (int mr = 0; mr < 2; ++mr)
                #pragma unroll
                for (int nr = 0; nr < 2; ++nr)
                    acc[mr][nr] = __builtin_amdgcn_mfma_f32_16x16x32_bf16(afh[mr], bfh[nr], acc[mr][nr], 0, 0, 0);
        }
        __syncthreads();
    }
    int crow = (lane >> 4) * 4;
    int ccol = lane & 15;
    #pragma unroll
    for (int mr = 0; mr < 2; ++mr) {
        #pragma unroll
        for (int nr = 0; nr < 2; ++nr) {
            int jc = j0 + wn * 32 + nr * 16 + ccol;
            #pragma unroll
            for (int jr = 0; jr < 4; ++jr) {
                int i = i0 + wm * 32 + mr * 16 + crow + jr;
                unsafeAtomicAdd(&S[(size_t)i * n + jc], acc[mr][nr][jr]);
            }
        }
    }
}

// ---------------- row softmax stats ----------------
__global__ __launch_bounds__(TPB) void row_stats_kernel(
    const float* __restrict__ S, float* __restrict__ rm, float* __restrict__ inv_rs, int n) {
    int row = blockIdx.x;
    const float* p = S + (size_t)row * n;
    float v[8];
    int cnt = 0;
    float mx = -INFINITY;
    for (int t = threadIdx.x; t < n; t += TPB) {
        v[cnt] = p[t];
        mx = fmaxf(mx, v[cnt]);
        ++cnt;
    }
    __shared__ float red[TPB];
    red[threadIdx.x] = mx;
    __syncthreads();
    for (int s = TPB / 2; s > 0; s >>= 1) {
        if (threadIdx.x < s) red[threadIdx.x] = fmaxf(red[threadIdx.x], red[threadIdx.x + s]);
        __syncthreads();
    }
    float gm = red[0];
    __syncthreads();
    float sum = 0.f;
    for (int u = 0; u < cnt; ++u) sum += __expf(v[u] - gm);
    red[threadIdx.x] = sum;
    __syncthreads();
    for (int s = TPB / 2; s > 0; s >>= 1) {
        if (threadIdx.x < s) red[threadIdx.x] += red[threadIdx.x + s];
        __syncthreads();
    }
    if (threadIdx.x == 0) { rm[row] = gm; inv_rs[row] = 1.f / red[0]; }
}

// ---------------- column softmax stats ----------------
__global__ __launch_bounds__(TPB) void col_stats_partial(
    const float* __restrict__ S, float* __restrict__ pm, float* __restrict__ ps,
    int n, int rows_per) {
    int col = blockIdx.x * TPB + threadIdx.x;
    int r0 = blockIdx.y * rows_per;
    float mx = -INFINITY, s = 0.f;
    for (int i = 0; i < rows_per; ++i) {
        float v = S[(size_t)(r0 + i) * n + col];
        if (v <= mx) {
            s += __expf(v - mx);
        } else {
            s = s * __expf(mx - v) + 1.f;
            mx = v;
        }
    }
    pm[(size_t)blockIdx.y * n + col] = mx;
    ps[(size_t)blockIdx.y * n + col] = s;
}

__global__ __launch_bounds__(TPB) void col_stats_merge(
    const float* __restrict__ pm, const float* __restrict__ ps,
    float* __restrict__ cm, float* __restrict__ inv_cs, int n, int chunks) {
    int col = blockIdx.x * TPB + threadIdx.x;
    float mx = -INFINITY;
    for (int c = 0; c < chunks; ++c) mx = fmaxf(mx, pm[(size_t)c * n + col]);
    float s = 0.f;
    for (int c = 0; c < chunks; ++c) s += ps[(size_t)c * n + col] * __expf(pm[(size_t)c * n + col] - mx);
    cm[col] = mx;
    inv_cs[col] = 1.f / s;
}

// ---------------- MFMA GEMM: a_alpha partials: out[z] = softmax_row(S[:, zchunk]) @ u_c[zchunk] ----------------
__global__ __launch_bounds__(TPB) void aalpha_mfma(
    const float* __restrict__ S, const float* __restrict__ rm, const float* __restrict__ irs,
    const u16* __restrict__ ucT, float* __restrict__ aalpha_part,
    const int* __restrict__ flagp, int m, int n, int d, int jsplit) {
    __shared__ u16 sA[4096];
    __shared__ u16 sB[4096];
    int fl = *flagp;
    int tid = threadIdx.x;
    int lane = tid & 63, wave = tid >> 6;
    int wm = wave >> 1, wn = wave & 1;
    int lrow = lane & 15, g = lane >> 4;
    int i0 = blockIdx.y * 64, kc0 = blockIdx.x * 64;
    int jchunk = n / jsplit;
    int jbeg = blockIdx.z * jchunk;
    float* outp = aalpha_part + (size_t)blockIdx.z * m * d;
    f32x4 acc[2][2];
    #pragma unroll
    for (int a = 0; a < 2; ++a)
        #pragma unroll
        for (int b = 0; b < 2; ++b) acc[a][b] = (f32x4){0.f, 0.f, 0.f, 0.f};

    for (int j0 = jbeg; j0 < jbeg + jchunk; j0 += 64) {
        #pragma unroll
        for (int it = 0; it < 4; ++it) {
            int id = tid + it * TPB;
            int row = id >> 4;
            int cq = id & 15;
            float4 sv = *(const float4*)(S + (size_t)(i0 + row) * n + j0 + cq * 4);
            float mi = rm[i0 + row], sc = irs[i0 + row];
            int p = fl ? (32 * (cq >> 3) + (cq & 3) * 8 + ((cq >> 2) & 1) * 4) : cq * 4;
            int boff = (row * 128 + p * 2) ^ ((row & 7) << 4);
            u16x4 pv = {f2bf(__expf(sv.x - mi) * sc), f2bf(__expf(sv.y - mi) * sc),
                        f2bf(__expf(sv.z - mi) * sc), f2bf(__expf(sv.w - mi) * sc)};
            *(u16x4*)((char*)sA + boff) = pv;
        }
        #pragma unroll
        for (int it = 0; it < 2; ++it) {
            int id = tid + it * TPB;
            int row = id >> 3, slot = id & 7;
            int boff = (row * 128 + slot * 16) ^ ((row & 7) << 4);
            *(int4*)((char*)sB + boff) = *(const int4*)(ucT + (size_t)(kc0 + row) * n + j0 + slot * 8);
        }
        __syncthreads();
        #pragma unroll
        for (int kk = 0; kk < 2; ++kk) {
            bf16x8 av[2], bv[2];
            #pragma unroll
            for (int mr = 0; mr < 2; ++mr) {
                int row = wm * 32 + mr * 16 + lrow;
                int boff = (row * 128 + kk * 64 + g * 16) ^ ((row & 7) << 4);
                av[mr] = *(const bf16x8*)((const char*)sA + boff);
            }
            #pragma unroll
            for (int nr = 0; nr < 2; ++nr) {
                int row = wn * 32 + nr * 16 + lrow;
                int boff = (row * 128 + kk * 64 + g * 16) ^ ((row & 7) << 4);
                bv[nr] = *(const bf16x8*)((const char*)sB + boff);
            }
            #pragma unroll
            for (int mr = 0; mr < 2; ++mr)
                #pragma unroll
                for (int nr = 0; nr < 2; ++nr)
                    acc[mr][nr] = __builtin_amdgcn_mfma_f32_16x16x32_bf16(av[mr], bv[nr], acc[mr][nr], 0, 0, 0);
        }
        __syncthreads();
    }
    int crow = (lane >> 4) * 4;
    int ccol = lane & 15;
    #pragma unroll
    for (int mr = 0; mr < 2; ++mr)
        #pragma unroll
        for (int nr = 0; nr < 2; ++nr) {
            int kc = kc0 + wn * 32 + nr * 16 + ccol;
            #pragma unroll
            for (int jr = 0; jr < 4; ++jr) {
                int i = i0 + wm * 32 + mr * 16 + crow + jr;
                outp[(size_t)i * d + kc] = acc[mr][nr][jr];
            }
        }
}

// ---------------- MFMA GEMM: a_beta partials: out[z] = softmax_col(S[zchunk,:])^T @ u_p[zchunk] ----------------
__global__ __launch_bounds__(TPB) void abeta_mfma(
    const float* __restrict__ S, const float* __restrict__ cm, const float* __restrict__ ics,
    const u16* __restrict__ upT, float* __restrict__ abeta_part,
    const int* __restrict__ flagp, int m, int n, int d, int isplit) {
    __shared__ u16 sA[4096];
    __shared__ u16 sB[4096];
    int fl = *flagp;
    int tid = threadIdx.x;
    int lane = tid & 63, wave = tid >> 6;
    int wm = wave >> 1, wn = wave & 1;
    int lrow = lane & 15, g = lane >> 4;
    int jb0 = blockIdx.y * 64, kc0 = blockIdx.x * 64;
    int ichunk = m / isplit;
    int ibeg = blockIdx.z * ichunk;
    float* outp = abeta_part + (size_t)blockIdx.z * n * d;
    f32x4 acc[2][2];
    #pragma unroll
    for (int a = 0; a < 2; ++a)
        #pragma unroll
        for (int b = 0; b < 2; ++b) acc[a][b] = (f32x4){0.f, 0.f, 0.f, 0.f};

    for (int i0 = ibeg; i0 < ibeg + ichunk; i0 += 64) {
        #pragma unroll
        for (int it = 0; it < 4; ++it) {
            int id = tid + it * TPB;
            int r = id >> 4;
            int cq = id & 15;
            float4 sv = *(const float4*)(S + (size_t)(i0 + r) * n + jb0 + cq * 4);
            float4 mj = *(const float4*)(cm + jb0 + cq * 4);
            float4 sj = *(const float4*)(ics + jb0 + cq * 4);
            int pi;
            if (fl) { int r5 = r & 31; pi = 32 * (r >> 5) + ((r5 >> 2) & 3) * 8 + (r5 >> 4) * 4 + (r5 & 3); }
            else pi = r;
            u16 v0 = f2bf(__expf(sv.x - mj.x) * sj.x);
            u16 v1 = f2bf(__expf(sv.y - mj.y) * sj.y);
            u16 v2 = f2bf(__expf(sv.z - mj.z) * sj.z);
            u16 v3 = f2bf(__expf(sv.w - mj.w) * sj.w);
            int j = cq * 4;
            *(u16*)((char*)sA + ((((j + 0) * 128) + pi * 2) ^ (((j + 0) & 7) << 4))) = v0;
            *(u16*)((char*)sA + ((((j + 1) * 128) + pi * 2) ^ (((j + 1) & 7) << 4))) = v1;
            *(u16*)((char*)sA + ((((j + 2) * 128) + pi * 2) ^ (((j + 2) & 7) << 4))) = v2;
            *(u16*)((char*)sA + ((((j + 3) * 128) + pi * 2) ^ (((j + 3) & 7) << 4))) = v3;
        }
        #pragma unroll
        for (int it = 0; it < 2; ++it) {
            int id = tid + it * TPB;
            int row = id >> 3, slot = id & 7;
            int boff = (row * 128 + slot * 16) ^ ((row & 7) << 4);
            *(int4*)((char*)sB + boff) = *(const int4*)(upT + (size_t)(kc0 + row) * m + i0 + slot * 8);
        }
        __syncthreads();
        #pragma unroll
        for (int kk = 0; kk < 2; ++kk) {
            bf16x8 av[2], bv[2];
            #pragma unroll
            for (int mr = 0; mr < 2; ++mr) {
                int row = wm * 32 + mr * 16 + lrow;
                int boff = (row * 128 + kk * 64 + g * 16) ^ ((row & 7) << 4);
                av[mr] = *(const bf16x8*)((const char*)sA + boff);
            }
            #pragma unroll
            for (int nr = 0; nr < 2; ++nr) {
                int row = wn * 32 + nr * 16 + lrow;
                int boff = (row * 128 + kk * 64 + g * 16) ^ ((row & 7) << 4);
                bv[nr] = *(const bf16x8*)((const char*)sB + boff);
            }
            #pragma unroll
            for (int mr = 0; mr < 2; ++mr)
                #pragma unroll
                for (int nr = 0; nr < 2; ++nr)
                    acc[mr][nr] = __builtin_amdgcn_mfma_f32_16x16x32_bf16(av[mr], bv[nr], acc[mr][nr], 0, 0, 0);
        }
        __syncthreads();
    }
    int crow = (lane >> 4) * 4;
    int ccol = lane & 15;
    #pragma unroll
    for (int mr = 0; mr < 2; ++mr)
        #pragma unroll
        for (int nr = 0; nr < 2; ++nr) {
            int kc = kc0 + wn * 32 + nr * 16 + ccol;
            #pragma unroll
            for (int jr = 0; jr < 4; ++jr) {
                int j = jb0 + wm * 32 + mr * 16 + crow + jr;
                outp[(size_t)j * d + kc] = acc[mr][nr][jr];
            }
        }
}

// ---------------- fused final dot, stage 1 (sums the z-partials inline) ----------------
__global__ __launch_bounds__(TPB) void final_stage1(
    const float* __restrict__ u_p, const float* __restrict__ u_c,
    const float* __restrict__ aa0, const float* __restrict__ aa1,
    const float* __restrict__ ab0, const float* __restrict__ ab1,
    const float* __restrict__ W, float* __restrict__ partials, int n, int d) {
    size_t total = (size_t)n * d / 4;
    float acc = 0.f;
    for (size_t q = (size_t)blockIdx.x * TPB + threadIdx.x; q < total;
         q += (size_t)gridDim.x * TPB) {
        size_t e = q * 4;
        int i = (int)(e / d);
        int k = (int)(e % d);
        size_t base = (size_t)i * d + k;
        float4 up = *(const float4*)(u_p + base);
        float4 a0 = *(const float4*)(aa0 + base);
        float4 a1 = *(const float4*)(aa1 + base);
        float4 uc = *(const float4*)(u_c + base);
        float4 b0 = *(const float4*)(ab0 + base);
        float4 b1 = *(const float4*)(ab1 + base);
        float4 aa = {a0.x + a1.x, a0.y + a1.y, a0.z + a1.z, a0.w + a1.w};
        float4 ab = {b0.x + b1.x, b0.y + b1.y, b0.z + b1.z, b0.w + b1.w};
        const float* wr = W + (size_t)i * 4 * d;
        float4 w0 = *(const float4*)(wr + k);
        float4 w1 = *(const float4*)(wr + d + k);
        float4 w2 = *(const float4*)(wr + 2 * d + k);
        float4 w3 = *(const float4*)(wr + 3 * d + k);
        acc += up.x * w0.x + aa.x * (w1.x + up.x * w2.x) + uc.x * ab.x * w3.x;
        acc += up.y * w0.y + aa.y * (w1.y + up.y * w2.y) + uc.y * ab.y * w3.y;
        acc += up.z * w0.z + aa.z * (w1.z + up.z * w2.z) + uc.z * ab.z * w3.z;
        acc += up.w * w0.w + aa.w * (w1.w + up.w * w2.w) + uc.w * ab.w * w3.w;
    }
    __shared__ float red[TPB];
    red[threadIdx.x] = acc;
    __syncthreads();
    for (int s = TPB / 2; s > 0; s >>= 1) {
        if (threadIdx.x < s) red[threadIdx.x] += red[threadIdx.x + s];
        __syncthreads();
    }
    if (threadIdx.x == 0) partials[blockIdx.x] = red[0];
}

__global__ __launch_bounds__(TPB) void final_stage2(
    const float* __restrict__ partials, int np, const float* __restrict__ bias,
    float* __restrict__ out) {
    double acc = 0.0;
    for (int t = threadIdx.x; t < np; t += TPB) acc += (double)partials[t];
    __shared__ double red[TPB];
    red[threadIdx.x] = acc;
    __syncthreads();
    for (int s = TPB / 2; s > 0; s >>= 1) {
        if (threadIdx.x < s) red[threadIdx.x] += red[threadIdx.x + s];
        __syncthreads();
    }
    if (threadIdx.x == 0) {
        double v = red[0] + (double)bias[0];
        out[0] = (float)(v > 0.0 ? v : 0.0);
    }
}

extern "C" void kernel_launch(void* const* d_in, const int* in_sizes, int n_in,
                              void* d_out, int out_size, void* d_ws, size_t ws_size,
                              hipStream_t stream) {
    const float* u_p = (const float*)d_in[0];
    const float* u_c = (const float*)d_in[1];
    const float* w_a = (const float*)d_in[2];
    const float* ffn_w = (const float*)d_in[3];
    const float* ffn_b = (const float*)d_in[4];
    float* out = (float*)d_out;

    int d = in_sizes[2] / 3;   // 2048
    int m = in_sizes[0] / d;   // 1024
    int n = in_sizes[1] / d;   // 1024
    const int CHUNKS = 64;
    const int NBLK_FINAL = 2048;
    const int KSPLIT = 8;      // gemmS:   2048 blocks = 8/CU (16 KB LDS fits)
    const int JSPLIT = 2;      // aalpha:  1024 blocks = 4/CU
    const int ISPLIT = 2;      // abeta:   1024 blocks = 4/CU

    size_t md = (size_t)m * d, nd = (size_t)n * d, mn = (size_t)m * n;

    float* ws = (float*)d_ws;
    float* r = ws;                      // m
    float* c = r + m;                   // n
    float* rm = c + n;                  // m
    float* inv_rs = rm + m;             // m
    float* cm = inv_rs + m;             // n
    float* inv_cs = cm + n;             // n
    float* pm = inv_cs + n;             // CHUNKS*n
    float* ps = pm + (size_t)CHUNKS * n;
    float* partials = ps + (size_t)CHUNKS * n;  // NBLK_FINAL
    int* flagp = (int*)(partials + NBLK_FINAL);
    float* S = (float*)(flagp + 16);
    float* aalpha = S + mn;             // JSPLIT * md  (partials)
    float* abeta = aalpha + (size_t)JSPLIT * md;  // ISPLIT * nd (partials)
    u16* upw3 = (u16*)(abeta + (size_t)ISPLIT * nd);
    u16* ucb = upw3 + md;
    u16* ucT = ucb + nd;
    u16* upT = ucT + nd;

    probe_kernel<<<1, 64, 0, stream>>>(flagp);
    bias_kernel<<<m + n, TPB, 0, stream>>>(u_p, u_c, w_a, r, c, m, n, d);
    convert_kernel<<<2048, TPB, 0, stream>>>(u_p, u_c, w_a, upw3, ucb, flagp, m, n, d);
    dim3 gtc(d / 64, n / 64);
    transpose_kernel<<<gtc, TPB, 0, stream>>>(u_c, ucT, flagp, n, d);
    dim3 gtp(d / 64, m / 64);
    transpose_kernel<<<gtp, TPB, 0, stream>>>(u_p, upT, flagp, m, d);

    initS_kernel<<<(m * (n / 4) + TPB - 1) / TPB, TPB, 0, stream>>>(r, c, S, m, n);

    dim3 gS(n / 64, m / 64, KSPLIT);
    gemmS_mfma<<<gS, TPB, 0, stream>>>(upw3, ucb, S, n, d, KSPLIT);

    row_stats_kernel<<<m, TPB, 0, stream>>>(S, rm, inv_rs, n);
    dim3 gCP(n / TPB, CHUNKS);
    col_stats_partial<<<gCP, TPB, 0, stream>>>(S, pm, ps, n, m / CHUNKS);
    col_stats_merge<<<n / TPB, TPB, 0, stream>>>(pm, ps, cm, inv_cs, n, CHUNKS);

    dim3 gA(d / 64, m / 64, JSPLIT);
    aalpha_mfma<<<gA, TPB, 0, stream>>>(S, rm, inv_rs, ucT, aalpha, flagp, m, n, d, JSPLIT);
    dim3 gB(d / 64, n / 64, ISPLIT);
    abeta_mfma<<<gB, TPB, 0, stream>>>(S, cm, inv_cs, upT, abeta, flagp, m, n, d, ISPLIT);

    final_stage1<<<NBLK_FINAL, TPB, 0, stream>>>(u_p, u_c, aalpha, aalpha + md,
                                                 abeta, abeta + nd, ffn_w,
                                                 partials, n, d);
    final_stage2<<<1, TPB, 0, stream>>>(partials, NBLK_FINAL, ffn_b, out);

    (void)out_size; (void)ws_size; (void)n_in;
}

// Round 7
// 98.585 us; speedup vs baseline: 1.8798x; 1.7211x over previous
//
#include <hip/hip_runtime.h>
#include <math.h>

#define TPB 256

typedef unsigned short u16;
typedef short bf16x8 __attribute__((ext_vector_type(8)));
typedef unsigned short u16x4 __attribute__((ext_vector_type(4)));
typedef float f32x4 __attribute__((ext_vector_type(4)));

__device__ __forceinline__ u16 f2bf(float x) {
    unsigned u = __float_as_uint(x);
    unsigned r = u + 0x7fffu + ((u >> 16) & 1u);
    return (u16)(r >> 16);
}
// k-permutation within a 32-wide chunk (half-split fragment layout). Applied
// consistently to BOTH GEMM operands, so correctness holds regardless of the
// hardware fragment k-order (sum over k is permutation-invariant).
__device__ __forceinline__ int pos32(int kk) {
    return ((kk >> 2) & 3) * 8 + (kk >> 4) * 4 + (kk & 3);
}

// ---------------- kernel 1: prep = bias + convert + 2 transposes (block roles) ----------------
__global__ __launch_bounds__(TPB) void prep_kernel(
    const float* __restrict__ up, const float* __restrict__ uc,
    const float* __restrict__ wa,
    u16* __restrict__ upw3, u16* __restrict__ ucb,
    u16* __restrict__ ucT, u16* __restrict__ upT,
    float* __restrict__ r, float* __restrict__ c,
    int m, int n, int d, int nTc, int nTp, int nCv, int nBs) {
    __shared__ float t[64 * 65];
    int b = blockIdx.x;
    int tid = threadIdx.x;

    if (b < nTc + nTp) {
        // ---- transpose role: src[rows][d] f32 -> dst[d][rows] bf16 (perm on row idx) ----
        const float* src; u16* dst; int rows; int tt;
        if (b < nTc) { src = uc; dst = ucT; rows = n; tt = b; }
        else         { src = up; dst = upT; rows = m; tt = b - nTc; }
        int ntx = d / 64;
        int c0 = (tt % ntx) * 64;
        int r0 = (tt / ntx) * 64;
        #pragma unroll
        for (int it = 0; it < 4; ++it) {
            int rr = (tid >> 4) + it * 16;
            int cc = (tid & 15) * 4;
            float4 v = *(const float4*)(src + (size_t)(r0 + rr) * d + c0 + cc);
            t[(cc + 0) * 65 + rr] = v.x;
            t[(cc + 1) * 65 + rr] = v.y;
            t[(cc + 2) * 65 + rr] = v.z;
            t[(cc + 3) * 65 + rr] = v.w;
        }
        __syncthreads();
        #pragma unroll
        for (int it = 0; it < 2; ++it) {
            int id = tid + it * TPB;
            int kc = id >> 3;
            int s = id & 7;
            u16 outv[8];
            #pragma unroll
            for (int e = 0; e < 8; ++e) {
                int p = s * 8 + e;
                int p5 = p & 31;
                int jloc = 32 * (p >> 5) + 16 * ((p5 >> 2) & 1) + 4 * (p5 >> 3) + (p5 & 3);
                outv[e] = f2bf(t[kc * 65 + jloc]);
            }
            *(u16x4*)(dst + (size_t)(c0 + kc) * rows + r0 + s * 8) = *(u16x4*)&outv[0];
            *(u16x4*)(dst + (size_t)(c0 + kc) * rows + r0 + s * 8 + 4) = *(u16x4*)&outv[4];
        }
    } else if (b < nTc + nTp + nCv) {
        // ---- convert role: upw3 = bf16(u_p*w3), ucb = bf16(u_c), permuted k ----
        int bb = b - nTc - nTp;
        const float* w3 = wa + 2 * d;
        int dq = d / 4;
        int qup = m * dq;
        int qtot = (m + n) * dq;
        for (int q = bb * TPB + tid; q < qtot; q += nCv * TPB) {
            if (q < qup) {
                int row = q / dq;
                int k = (q - row * dq) * 4;
                float4 v = *(const float4*)(up + (size_t)row * d + k);
                float4 w = *(const float4*)(w3 + k);
                int p = (k & ~31) + pos32(k & 31);
                u16x4 hi = {f2bf(v.x * w.x), f2bf(v.y * w.y), f2bf(v.z * w.z), f2bf(v.w * w.w)};
                *(u16x4*)(upw3 + (size_t)row * d + p) = hi;
            } else {
                int q2 = q - qup;
                int row = q2 / dq;
                int k = (q2 - row * dq) * 4;
                float4 v = *(const float4*)(uc + (size_t)row * d + k);
                int p = (k & ~31) + pos32(k & 31);
                u16x4 hi = {f2bf(v.x), f2bf(v.y), f2bf(v.z), f2bf(v.w)};
                *(u16x4*)(ucb + (size_t)row * d + p) = hi;
            }
        }
    } else {
        // ---- bias role: r[i]=u_p[i]·w1, c[j]=u_c[j]·w2 ; 8 rows/block, 2 rows/wave ----
        int bb = b - nTc - nTp - nCv;
        int lane = tid & 63, wave = tid >> 6;
        for (int q = wave; q < 8; q += 4) {
            int row = bb * 8 + q;
            const float* src; const float* w; float* dst;
            if (row < m) { src = up + (size_t)row * d;       w = wa;     dst = r + row; }
            else         { src = uc + (size_t)(row - m) * d; w = wa + d; dst = c + (row - m); }
            float acc = 0.f;
            for (int k4 = lane; k4 < d / 4; k4 += 64) {
                float4 a = ((const float4*)src)[k4];
                float4 ww = ((const float4*)w)[k4];
                acc += a.x * ww.x + a.y * ww.y + a.z * ww.z + a.w * ww.w;
            }
            #pragma unroll
            for (int off = 32; off > 0; off >>= 1) acc += __shfl_down(acc, off);
            if (lane == 0) *dst = acc;
        }
    }
}

// ---------------- kernel 2: gemmS partials: Sp[z] = upw3 @ ucb^T over k-chunk z (plain stores) ----------------
__global__ __launch_bounds__(TPB) void gemmS_mfma(
    const u16* __restrict__ Ah, const u16* __restrict__ Bh,
    float* __restrict__ Sp, int m, int n, int d, int ksplit) {
    __shared__ u16 sAh[4096];
    __shared__ u16 sBh[4096];
    int tid = threadIdx.x;
    int lane = tid & 63, wave = tid >> 6;
    int wm = wave >> 1, wn = wave & 1;
    int lrow = lane & 15, g = lane >> 4;
    int i0 = blockIdx.y * 64, j0 = blockIdx.x * 64;
    int kchunk = d / ksplit;
    int kbeg = blockIdx.z * kchunk;
    float* outS = Sp + (size_t)blockIdx.z * m * n;
    f32x4 acc[2][2];
    #pragma unroll
    for (int a = 0; a < 2; ++a)
        #pragma unroll
        for (int bq = 0; bq < 2; ++bq) acc[a][bq] = (f32x4){0.f, 0.f, 0.f, 0.f};

    for (int k0 = kbeg; k0 < kbeg + kchunk; k0 += 64) {
        #pragma unroll
        for (int it = 0; it < 2; ++it) {
            int id = tid + it * TPB;
            int row = id >> 3, slot = id & 7;
            int boff = (row * 128 + slot * 16) ^ ((row & 7) << 4);
            *(int4*)((char*)sAh + boff) = *(const int4*)(Ah + (size_t)(i0 + row) * d + k0 + slot * 8);
            *(int4*)((char*)sBh + boff) = *(const int4*)(Bh + (size_t)(j0 + row) * d + k0 + slot * 8);
        }
        __syncthreads();
        #pragma unroll
        for (int kk = 0; kk < 2; ++kk) {
            bf16x8 afh[2], bfh[2];
            #pragma unroll
            for (int mr = 0; mr < 2; ++mr) {
                int row = wm * 32 + mr * 16 + lrow;
                int boff = (row * 128 + kk * 64 + g * 16) ^ ((row & 7) << 4);
                afh[mr] = *(const bf16x8*)((const char*)sAh + boff);
            }
            #pragma unroll
            for (int nr = 0; nr < 2; ++nr) {
                int row = wn * 32 + nr * 16 + lrow;
                int boff = (row * 128 + kk * 64 + g * 16) ^ ((row & 7) << 4);
                bfh[nr] = *(const bf16x8*)((const char*)sBh + boff);
            }
            #pragma unroll
            for (int mr = 0; mr < 2; ++mr)
                #pragma unroll
                for (int nr = 0; nr < 2; ++nr)
                    acc[mr][nr] = __builtin_amdgcn_mfma_f32_16x16x32_bf16(afh[mr], bfh[nr], acc[mr][nr], 0, 0, 0);
        }
        __syncthreads();
    }
    int crow = (lane >> 4) * 4;
    int ccol = lane & 15;
    #pragma unroll
    for (int mr = 0; mr < 2; ++mr)
        #pragma unroll
        for (int nr = 0; nr < 2; ++nr) {
            int jc = j0 + wn * 32 + nr * 16 + ccol;
            #pragma unroll
            for (int jr = 0; jr < 4; ++jr) {
                int i = i0 + wm * 32 + mr * 16 + crow + jr;
                outS[(size_t)i * n + jc] = acc[mr][nr][jr];
            }
        }
}

// ---------------- kernel 3: stats = combine Sp + r + c -> S, row stats (final), col partials ----------------
__global__ __launch_bounds__(TPB) void stats_kernel(
    const float* __restrict__ Sp, const float* __restrict__ r, const float* __restrict__ c,
    float* __restrict__ S, float* __restrict__ rm, float* __restrict__ inv_rs,
    float* __restrict__ pm, float* __restrict__ ps, int m, int n) {
    __shared__ float red[TPB];
    int tid = threadIdx.x;
    int col = tid * 4;
    size_t mn = (size_t)m * n;
    float4 cv = *(const float4*)(c + col);
    float v[4][4];
    #pragma unroll
    for (int rr = 0; rr < 4; ++rr) {
        int row = blockIdx.x * 4 + rr;
        size_t base = (size_t)row * n + col;
        float4 a0 = *(const float4*)(Sp + base);
        float4 a1 = *(const float4*)(Sp + mn + base);
        float4 a2 = *(const float4*)(Sp + 2 * mn + base);
        float4 a3 = *(const float4*)(Sp + 3 * mn + base);
        float rv = r[row];
        float4 o;
        o.x = a0.x + a1.x + a2.x + a3.x + rv + cv.x;
        o.y = a0.y + a1.y + a2.y + a3.y + rv + cv.y;
        o.z = a0.z + a1.z + a2.z + a3.z + rv + cv.z;
        o.w = a0.w + a1.w + a2.w + a3.w + rv + cv.w;
        *(float4*)(S + base) = o;
        v[rr][0] = o.x; v[rr][1] = o.y; v[rr][2] = o.z; v[rr][3] = o.w;
    }
    // row stats (rows are fully inside this block)
    #pragma unroll
    for (int rr = 0; rr < 4; ++rr) {
        float lm = fmaxf(fmaxf(v[rr][0], v[rr][1]), fmaxf(v[rr][2], v[rr][3]));
        red[tid] = lm;
        __syncthreads();
        for (int s = TPB / 2; s > 0; s >>= 1) {
            if (tid < s) red[tid] = fmaxf(red[tid], red[tid + s]);
            __syncthreads();
        }
        float gm = red[0];
        __syncthreads();
        float ls = __expf(v[rr][0] - gm) + __expf(v[rr][1] - gm) +
                   __expf(v[rr][2] - gm) + __expf(v[rr][3] - gm);
        red[tid] = ls;
        __syncthreads();
        for (int s = TPB / 2; s > 0; s >>= 1) {
            if (tid < s) red[tid] += red[tid + s];
            __syncthreads();
        }
        if (tid == 0) {
            int row = blockIdx.x * 4 + rr;
            rm[row] = gm;
            inv_rs[row] = 1.f / red[0];
        }
        __syncthreads();
    }
    // col partial stats (chunk = blockIdx.x covers 4 rows)
    #pragma unroll
    for (int e = 0; e < 4; ++e) {
        float cmx = fmaxf(fmaxf(v[0][e], v[1][e]), fmaxf(v[2][e], v[3][e]));
        float cs = __expf(v[0][e] - cmx) + __expf(v[1][e] - cmx) +
                   __expf(v[2][e] - cmx) + __expf(v[3][e] - cmx);
        pm[(size_t)blockIdx.x * n + col + e] = cmx;
        ps[(size_t)blockIdx.x * n + col + e] = cs;
    }
}

// ---------------- kernel 4: col merge (two-level; 16 cols x 16 groups per block) ----------------
__global__ __launch_bounds__(TPB) void col_merge(
    const float* __restrict__ pm, const float* __restrict__ ps,
    float* __restrict__ cmv, float* __restrict__ ics, int n, int chunks) {
    __shared__ float sm[TPB], ss[TPB];
    int colLocal = threadIdx.x & 15;
    int grp = threadIdx.x >> 4;         // 0..15
    int col = blockIdx.x * 16 + colLocal;
    int per = chunks / 16;
    float mx = -INFINITY, s = 0.f;
    for (int cc = grp * per; cc < (grp + 1) * per; ++cc) {
        float pmv = pm[(size_t)cc * n + col];
        float psv = ps[(size_t)cc * n + col];
        if (pmv <= mx) {
            s += psv * __expf(pmv - mx);
        } else {
            s = s * __expf(mx - pmv) + psv;
            mx = pmv;
        }
    }
    sm[threadIdx.x] = mx; ss[threadIdx.x] = s;
    __syncthreads();
    for (int st = 128; st >= 16; st >>= 1) {
        if (threadIdx.x < st) {
            float m1 = sm[threadIdx.x], s1 = ss[threadIdx.x];
            float m2 = sm[threadIdx.x + st], s2 = ss[threadIdx.x + st];
            float mo = fmaxf(m1, m2);
            ss[threadIdx.x] = s1 * __expf(m1 - mo) + s2 * __expf(m2 - mo);
            sm[threadIdx.x] = mo;
        }
        __syncthreads();
    }
    if (threadIdx.x < 16) {
        cmv[col] = sm[threadIdx.x];
        ics[col] = 1.f / ss[threadIdx.x];
    }
}

// ---------------- kernel 5: fused attn GEMMs: z<2 -> aalpha partial z ; z>=2 -> abeta partial z-2 ----------------
__global__ __launch_bounds__(TPB) void attn_mfma(
    const float* __restrict__ S, const float* __restrict__ rm, const float* __restrict__ irs,
    const float* __restrict__ cm, const float* __restrict__ ics,
    const u16* __restrict__ ucT, const u16* __restrict__ upT,
    float* __restrict__ aalpha_part, float* __restrict__ abeta_part,
    int m, int n, int d) {
    __shared__ u16 sA[4096];
    __shared__ u16 sB[4096];
    int tid = threadIdx.x;
    int lane = tid & 63, wave = tid >> 6;
    int wm = wave >> 1, wn = wave & 1;
    int lrow = lane & 15, g = lane >> 4;
    int kc0 = blockIdx.x * 64;
    int bz = blockIdx.z;
    f32x4 acc[2][2];
    #pragma unroll
    for (int a = 0; a < 2; ++a)
        #pragma unroll
        for (int bq = 0; bq < 2; ++bq) acc[a][bq] = (f32x4){0.f, 0.f, 0.f, 0.f};
    int crow = (lane >> 4) * 4;
    int ccol = lane & 15;

    if (bz < 2) {
        // ---- a_alpha partial: softmax_row(S[:, chunk]) @ u_c[chunk] ----
        int i0 = blockIdx.y * 64;
        int jchunk = n / 2;
        int jbeg = bz * jchunk;
        float* outp = aalpha_part + (size_t)bz * m * d;
        for (int j0 = jbeg; j0 < jbeg + jchunk; j0 += 64) {
            #pragma unroll
            for (int it = 0; it < 4; ++it) {
                int id = tid + it * TPB;
                int row = id >> 4;
                int cq = id & 15;
                float4 sv = *(const float4*)(S + (size_t)(i0 + row) * n + j0 + cq * 4);
                float mi = rm[i0 + row], sc = irs[i0 + row];
                int p = 32 * (cq >> 3) + (cq & 3) * 8 + ((cq >> 2) & 1) * 4;
                int boff = (row * 128 + p * 2) ^ ((row & 7) << 4);
                u16x4 pv = {f2bf(__expf(sv.x - mi) * sc), f2bf(__expf(sv.y - mi) * sc),
                            f2bf(__expf(sv.z - mi) * sc), f2bf(__expf(sv.w - mi) * sc)};
                *(u16x4*)((char*)sA + boff) = pv;
            }
            #pragma unroll
            for (int it = 0; it < 2; ++it) {
                int id = tid + it * TPB;
                int row = id >> 3, slot = id & 7;
                int boff = (row * 128 + slot * 16) ^ ((row & 7) << 4);
                *(int4*)((char*)sB + boff) = *(const int4*)(ucT + (size_t)(kc0 + row) * n + j0 + slot * 8);
            }
            __syncthreads();
            #pragma unroll
            for (int kk = 0; kk < 2; ++kk) {
                bf16x8 av[2], bv[2];
                #pragma unroll
                for (int mr = 0; mr < 2; ++mr) {
                    int row = wm * 32 + mr * 16 + lrow;
                    int boff = (row * 128 + kk * 64 + g * 16) ^ ((row & 7) << 4);
                    av[mr] = *(const bf16x8*)((const char*)sA + boff);
                }
                #pragma unroll
                for (int nr = 0; nr < 2; ++nr) {
                    int row = wn * 32 + nr * 16 + lrow;
                    int boff = (row * 128 + kk * 64 + g * 16) ^ ((row & 7) << 4);
                    bv[nr] = *(const bf16x8*)((const char*)sB + boff);
                }
                #pragma unroll
                for (int mr = 0; mr < 2; ++mr)
                    #pragma unroll
                    for (int nr = 0; nr < 2; ++nr)
                        acc[mr][nr] = __builtin_amdgcn_mfma_f32_16x16x32_bf16(av[mr], bv[nr], acc[mr][nr], 0, 0, 0);
            }
            __syncthreads();
        }
        #pragma unroll
        for (int mr = 0; mr < 2; ++mr)
            #pragma unroll
            for (int nr = 0; nr < 2; ++nr) {
                int kc = kc0 + wn * 32 + nr * 16 + ccol;
                #pragma unroll
                for (int jr = 0; jr < 4; ++jr) {
                    int i = i0 + wm * 32 + mr * 16 + crow + jr;
                    outp[(size_t)i * d + kc] = acc[mr][nr][jr];
                }
            }
    } else {
        // ---- a_beta partial: softmax_col(S[chunk,:])^T @ u_p[chunk] ----
        int jb0 = blockIdx.y * 64;
        int z = bz - 2;
        int ichunk = m / 2;
        int ibeg = z * ichunk;
        float* outp = abeta_part + (size_t)z * n * d;
        for (int i0 = ibeg; i0 < ibeg + ichunk; i0 += 64) {
            #pragma unroll
            for (int it = 0; it < 4; ++it) {
                int id = tid + it * TPB;
                int rr = id >> 4;
                int cq = id & 15;
                float4 sv = *(const float4*)(S + (size_t)(i0 + rr) * n + jb0 + cq * 4);
                float4 mj = *(const float4*)(cm + jb0 + cq * 4);
                float4 sj = *(const float4*)(ics + jb0 + cq * 4);
                int r5 = rr & 31;
                int pi = 32 * (rr >> 5) + ((r5 >> 2) & 3) * 8 + (r5 >> 4) * 4 + (r5 & 3);
                u16 v0 = f2bf(__expf(sv.x - mj.x) * sj.x);
                u16 v1 = f2bf(__expf(sv.y - mj.y) * sj.y);
                u16 v2 = f2bf(__expf(sv.z - mj.z) * sj.z);
                u16 v3 = f2bf(__expf(sv.w - mj.w) * sj.w);
                int j = cq * 4;
                *(u16*)((char*)sA + ((((j + 0) * 128) + pi * 2) ^ (((j + 0) & 7) << 4))) = v0;
                *(u16*)((char*)sA + ((((j + 1) * 128) + pi * 2) ^ (((j + 1) & 7) << 4))) = v1;
                *(u16*)((char*)sA + ((((j + 2) * 128) + pi * 2) ^ (((j + 2) & 7) << 4))) = v2;
                *(u16*)((char*)sA + ((((j + 3) * 128) + pi * 2) ^ (((j + 3) & 7) << 4))) = v3;
            }
            #pragma unroll
            for (int it = 0; it < 2; ++it) {
                int id = tid + it * TPB;
                int row = id >> 3, slot = id & 7;
                int boff = (row * 128 + slot * 16) ^ ((row & 7) << 4);
                *(int4*)((char*)sB + boff) = *(const int4*)(upT + (size_t)(kc0 + row) * m + i0 + slot * 8);
            }
            __syncthreads();
            #pragma unroll
            for (int kk = 0; kk < 2; ++kk) {
                bf16x8 av[2], bv[2];
                #pragma unroll
                for (int mr = 0; mr < 2; ++mr) {
                    int row = wm * 32 + mr * 16 + lrow;
                    int boff = (row * 128 + kk * 64 + g * 16) ^ ((row & 7) << 4);
                    av[mr] = *(const bf16x8*)((const char*)sA + boff);
                }
                #pragma unroll
                for (int nr = 0; nr < 2; ++nr) {
                    int row = wn * 32 + nr * 16 + lrow;
                    int boff = (row * 128 + kk * 64 + g * 16) ^ ((row & 7) << 4);
                    bv[nr] = *(const bf16x8*)((const char*)sB + boff);
                }
                #pragma unroll
                for (int mr = 0; mr < 2; ++mr)
                    #pragma unroll
                    for (int nr = 0; nr < 2; ++nr)
                        acc[mr][nr] = __builtin_amdgcn_mfma_f32_16x16x32_bf16(av[mr], bv[nr], acc[mr][nr], 0, 0, 0);
            }
            __syncthreads();
        }
        #pragma unroll
        for (int mr = 0; mr < 2; ++mr)
            #pragma unroll
            for (int nr = 0; nr < 2; ++nr) {
                int kc = kc0 + wn * 32 + nr * 16 + ccol;
                #pragma unroll
                for (int jr = 0; jr < 4; ++jr) {
                    int j = jb0 + wm * 32 + mr * 16 + crow + jr;
                    outp[(size_t)j * d + kc] = acc[mr][nr][jr];
                }
            }
    }
}

// ---------------- kernel 6: fused final dot, stage 1 ----------------
__global__ __launch_bounds__(TPB) void final_stage1(
    const float* __restrict__ u_p, const float* __restrict__ u_c,
    const float* __restrict__ aa0, const float* __restrict__ aa1,
    const float* __restrict__ ab0, const float* __restrict__ ab1,
    const float* __restrict__ W, float* __restrict__ partials, int n, int d) {
    size_t total = (size_t)n * d / 4;
    float acc = 0.f;
    for (size_t q = (size_t)blockIdx.x * TPB + threadIdx.x; q < total;
         q += (size_t)gridDim.x * TPB) {
        size_t e = q * 4;
        int i = (int)(e / d);
        int k = (int)(e % d);
        size_t base = (size_t)i * d + k;
        float4 up = *(const float4*)(u_p + base);
        float4 a0 = *(const float4*)(aa0 + base);
        float4 a1 = *(const float4*)(aa1 + base);
        float4 uc = *(const float4*)(u_c + base);
        float4 b0 = *(const float4*)(ab0 + base);
        float4 b1 = *(const float4*)(ab1 + base);
        float4 aa = {a0.x + a1.x, a0.y + a1.y, a0.z + a1.z, a0.w + a1.w};
        float4 ab = {b0.x + b1.x, b0.y + b1.y, b0.z + b1.z, b0.w + b1.w};
        const float* wr = W + (size_t)i * 4 * d;
        float4 w0 = *(const float4*)(wr + k);
        float4 w1 = *(const float4*)(wr + d + k);
        float4 w2 = *(const float4*)(wr + 2 * d + k);
        float4 w3 = *(const float4*)(wr + 3 * d + k);
        acc += up.x * w0.x + aa.x * (w1.x + up.x * w2.x) + uc.x * ab.x * w3.x;
        acc += up.y * w0.y + aa.y * (w1.y + up.y * w2.y) + uc.y * ab.y * w3.y;
        acc += up.z * w0.z + aa.z * (w1.z + up.z * w2.z) + uc.z * ab.z * w3.z;
        acc += up.w * w0.w + aa.w * (w1.w + up.w * w2.w) + uc.w * ab.w * w3.w;
    }
    __shared__ float red[TPB];
    red[threadIdx.x] = acc;
    __syncthreads();
    for (int s = TPB / 2; s > 0; s >>= 1) {
        if (threadIdx.x < s) red[threadIdx.x] += red[threadIdx.x + s];
        __syncthreads();
    }
    if (threadIdx.x == 0) partials[blockIdx.x] = red[0];
}

// ---------------- kernel 7: stage 2 ----------------
__global__ __launch_bounds__(TPB) void final_stage2(
    const float* __restrict__ partials, int np, const float* __restrict__ bias,
    float* __restrict__ out) {
    double acc = 0.0;
    for (int t = threadIdx.x; t < np; t += TPB) acc += (double)partials[t];
    __shared__ double red[TPB];
    red[threadIdx.x] = acc;
    __syncthreads();
    for (int s = TPB / 2; s > 0; s >>= 1) {
        if (threadIdx.x < s) red[threadIdx.x] += red[threadIdx.x + s];
        __syncthreads();
    }
    if (threadIdx.x == 0) {
        double v = red[0] + (double)bias[0];
        out[0] = (float)(v > 0.0 ? v : 0.0);
    }
}

extern "C" void kernel_launch(void* const* d_in, const int* in_sizes, int n_in,
                              void* d_out, int out_size, void* d_ws, size_t ws_size,
                              hipStream_t stream) {
    const float* u_p = (const float*)d_in[0];
    const float* u_c = (const float*)d_in[1];
    const float* w_a = (const float*)d_in[2];
    const float* ffn_w = (const float*)d_in[3];
    const float* ffn_b = (const float*)d_in[4];
    float* out = (float*)d_out;

    int d = in_sizes[2] / 3;   // 2048
    int m = in_sizes[0] / d;   // 1024
    int n = in_sizes[1] / d;   // 1024
    const int NBLK_FINAL = 2048;
    const int KSPLIT = 4;
    int chunks = m / 4;        // 256 col-stat chunks (from stats_kernel)

    size_t md = (size_t)m * d, nd = (size_t)n * d, mn = (size_t)m * n;

    float* ws = (float*)d_ws;
    float* r = ws;                       // m
    float* c = r + m;                    // n
    float* rm = c + n;                   // m
    float* inv_rs = rm + m;              // m
    float* cm = inv_rs + m;              // n
    float* inv_cs = cm + n;              // n
    float* pm = inv_cs + n;              // chunks*n
    float* ps = pm + (size_t)chunks * n; // chunks*n
    float* partials = ps + (size_t)chunks * n;   // NBLK_FINAL
    float* S = partials + NBLK_FINAL;    // mn
    float* Sp = S + mn;                  // KSPLIT*mn
    float* aalpha = Sp + (size_t)KSPLIT * mn;    // 2*md
    float* abeta = aalpha + 2 * md;      // 2*nd
    u16* upw3 = (u16*)(abeta + 2 * nd);  // md
    u16* ucb = upw3 + md;                // nd
    u16* ucT = ucb + nd;                 // nd
    u16* upT = ucT + nd;                 // md

    // prep: transposes + convert + bias in one launch
    int nTc = (d / 64) * (n / 64);   // 512
    int nTp = (d / 64) * (m / 64);   // 512
    int nCv = 256;
    int nBs = (m + n) / 8;           // 256
    prep_kernel<<<nTc + nTp + nCv + nBs, TPB, 0, stream>>>(
        u_p, u_c, w_a, upw3, ucb, ucT, upT, r, c, m, n, d, nTc, nTp, nCv, nBs);

    // S partials (no atomics)
    dim3 gS(n / 64, m / 64, KSPLIT);
    gemmS_mfma<<<gS, TPB, 0, stream>>>(upw3, ucb, Sp, m, n, d, KSPLIT);

    // combine + row stats + col partial stats
    stats_kernel<<<m / 4, TPB, 0, stream>>>(Sp, r, c, S, rm, inv_rs, pm, ps, m, n);

    // col merge
    col_merge<<<n / 16, TPB, 0, stream>>>(pm, ps, cm, inv_cs, n, chunks);

    // fused aalpha + abeta
    dim3 gA(d / 64, m / 64, 4);
    attn_mfma<<<gA, TPB, 0, stream>>>(S, rm, inv_rs, cm, inv_cs, ucT, upT,
                                      aalpha, abeta, m, n, d);

    final_stage1<<<NBLK_FINAL, TPB, 0, stream>>>(u_p, u_c, aalpha, aalpha + md,
                                                 abeta, abeta + nd, ffn_w,
                                                 partials, n, d);
    final_stage2<<<1, TPB, 0, stream>>>(partials, NBLK_FINAL, ffn_b, out);

    (void)out_size; (void)ws_size; (void)n_in;
}

// Round 8
// 82.881 us; speedup vs baseline: 2.2360x; 1.1895x over previous
//
#include <hip/hip_runtime.h>
#include <math.h>

#define TPB 256

typedef unsigned short u16;
typedef short bf16x8 __attribute__((ext_vector_type(8)));
typedef unsigned short u16x4 __attribute__((ext_vector_type(4)));
typedef float f32x4 __attribute__((ext_vector_type(4)));

__device__ __forceinline__ u16 f2bf(float x) {
    unsigned u = __float_as_uint(x);
    unsigned r = u + 0x7fffu + ((u >> 16) & 1u);
    return (u16)(r >> 16);
}
// k-permutation within a 32-wide chunk (half-split fragment layout). Applied
// consistently to BOTH GEMM operands -> correctness independent of HW k-order.
__device__ __forceinline__ int pos32(int kk) {
    return ((kk >> 2) & 3) * 8 + (kk >> 4) * 4 + (kk & 3);
}
// inverse of pos32 (position p -> original index), within 32-chunk
__device__ __forceinline__ int ipos32(int p5) {
    return 16 * ((p5 >> 2) & 1) + 4 * (p5 >> 3) + (p5 & 3);
}

// ---------------- kernel 1: prep = bias + convert + 2 transposes (block roles) ----------------
__global__ __launch_bounds__(TPB) void prep_kernel(
    const float* __restrict__ up, const float* __restrict__ uc,
    const float* __restrict__ wa,
    u16* __restrict__ upw3, u16* __restrict__ ucb,
    u16* __restrict__ ucT, u16* __restrict__ upT,
    float* __restrict__ r, float* __restrict__ c,
    int m, int n, int d, int nTc, int nTp, int nCv, int nBs) {
    __shared__ float t[64 * 65];
    int b = blockIdx.x;
    int tid = threadIdx.x;

    if (b < nTc + nTp) {
        // ---- transpose role: src[rows][d] f32 -> dst[d][rows] bf16 (perm on row idx) ----
        const float* src; u16* dst; int rows; int tt;
        if (b < nTc) { src = uc; dst = ucT; rows = n; tt = b; }
        else         { src = up; dst = upT; rows = m; tt = b - nTc; }
        int ntx = d / 64;
        int c0 = (tt % ntx) * 64;
        int r0 = (tt / ntx) * 64;
        #pragma unroll
        for (int it = 0; it < 4; ++it) {
            int rr = (tid >> 4) + it * 16;
            int cc = (tid & 15) * 4;
            float4 v = *(const float4*)(src + (size_t)(r0 + rr) * d + c0 + cc);
            t[(cc + 0) * 65 + rr] = v.x;
            t[(cc + 1) * 65 + rr] = v.y;
            t[(cc + 2) * 65 + rr] = v.z;
            t[(cc + 3) * 65 + rr] = v.w;
        }
        __syncthreads();
        #pragma unroll
        for (int it = 0; it < 2; ++it) {
            int id = tid + it * TPB;
            int kc = id >> 3;
            int s = id & 7;
            u16 outv[8];
            #pragma unroll
            for (int e = 0; e < 8; ++e) {
                int p = s * 8 + e;
                int jloc = 32 * (p >> 5) + ipos32(p & 31);
                outv[e] = f2bf(t[kc * 65 + jloc]);
            }
            *(u16x4*)(dst + (size_t)(c0 + kc) * rows + r0 + s * 8) = *(u16x4*)&outv[0];
            *(u16x4*)(dst + (size_t)(c0 + kc) * rows + r0 + s * 8 + 4) = *(u16x4*)&outv[4];
        }
    } else if (b < nTc + nTp + nCv) {
        // ---- convert role: upw3 = bf16(u_p*w3), ucb = bf16(u_c), permuted k ----
        int bb = b - nTc - nTp;
        const float* w3 = wa + 2 * d;
        int dq = d / 4;
        int qup = m * dq;
        int qtot = (m + n) * dq;
        for (int q = bb * TPB + tid; q < qtot; q += nCv * TPB) {
            if (q < qup) {
                int row = q / dq;
                int k = (q - row * dq) * 4;
                float4 v = *(const float4*)(up + (size_t)row * d + k);
                float4 w = *(const float4*)(w3 + k);
                int p = (k & ~31) + pos32(k & 31);
                u16x4 hi = {f2bf(v.x * w.x), f2bf(v.y * w.y), f2bf(v.z * w.z), f2bf(v.w * w.w)};
                *(u16x4*)(upw3 + (size_t)row * d + p) = hi;
            } else {
                int q2 = q - qup;
                int row = q2 / dq;
                int k = (q2 - row * dq) * 4;
                float4 v = *(const float4*)(uc + (size_t)row * d + k);
                int p = (k & ~31) + pos32(k & 31);
                u16x4 hi = {f2bf(v.x), f2bf(v.y), f2bf(v.z), f2bf(v.w)};
                *(u16x4*)(ucb + (size_t)row * d + p) = hi;
            }
        }
    } else {
        // ---- bias role: r[i]=u_p[i]·w1, c[j]=u_c[j]·w2 ; 8 rows/block, 2 rows/wave ----
        int bb = b - nTc - nTp - nCv;
        int lane = tid & 63, wave = tid >> 6;
        for (int q = wave; q < 8; q += 4) {
            int row = bb * 8 + q;
            const float* src; const float* w; float* dst;
            if (row < m) { src = up + (size_t)row * d;       w = wa;     dst = r + row; }
            else         { src = uc + (size_t)(row - m) * d; w = wa + d; dst = c + (row - m); }
            float acc = 0.f;
            for (int k4 = lane; k4 < d / 4; k4 += 64) {
                float4 a = ((const float4*)src)[k4];
                float4 ww = ((const float4*)w)[k4];
                acc += a.x * ww.x + a.y * ww.y + a.z * ww.z + a.w * ww.w;
            }
            #pragma unroll
            for (int off = 32; off > 0; off >>= 1) acc += __shfl_down(acc, off);
            if (lane == 0) *dst = acc;
        }
    }
}

// ---------------- kernel 2: gemmS partials: Sp[z] = upw3 @ ucb^T over k-chunk z ----------------
__global__ __launch_bounds__(TPB) void gemmS_mfma(
    const u16* __restrict__ Ah, const u16* __restrict__ Bh,
    float* __restrict__ Sp, int m, int n, int d, int ksplit) {
    __shared__ u16 sAh[4096];
    __shared__ u16 sBh[4096];
    int tid = threadIdx.x;
    int lane = tid & 63, wave = tid >> 6;
    int wm = wave >> 1, wn = wave & 1;
    int lrow = lane & 15, g = lane >> 4;
    int i0 = blockIdx.y * 64, j0 = blockIdx.x * 64;
    int kchunk = d / ksplit;
    int kbeg = blockIdx.z * kchunk;
    float* outS = Sp + (size_t)blockIdx.z * m * n;
    f32x4 acc[2][2];
    #pragma unroll
    for (int a = 0; a < 2; ++a)
        #pragma unroll
        for (int bq = 0; bq < 2; ++bq) acc[a][bq] = (f32x4){0.f, 0.f, 0.f, 0.f};

    for (int k0 = kbeg; k0 < kbeg + kchunk; k0 += 64) {
        #pragma unroll
        for (int it = 0; it < 2; ++it) {
            int id = tid + it * TPB;
            int row = id >> 3, slot = id & 7;
            int boff = (row * 128 + slot * 16) ^ ((row & 7) << 4);
            *(int4*)((char*)sAh + boff) = *(const int4*)(Ah + (size_t)(i0 + row) * d + k0 + slot * 8);
            *(int4*)((char*)sBh + boff) = *(const int4*)(Bh + (size_t)(j0 + row) * d + k0 + slot * 8);
        }
        __syncthreads();
        #pragma unroll
        for (int kk = 0; kk < 2; ++kk) {
            bf16x8 afh[2], bfh[2];
            #pragma unroll
            for (int mr = 0; mr < 2; ++mr) {
                int row = wm * 32 + mr * 16 + lrow;
                int boff = (row * 128 + kk * 64 + g * 16) ^ ((row & 7) << 4);
                afh[mr] = *(const bf16x8*)((const char*)sAh + boff);
            }
            #pragma unroll
            for (int nr = 0; nr < 2; ++nr) {
                int row = wn * 32 + nr * 16 + lrow;
                int boff = (row * 128 + kk * 64 + g * 16) ^ ((row & 7) << 4);
                bfh[nr] = *(const bf16x8*)((const char*)sBh + boff);
            }
            #pragma unroll
            for (int mr = 0; mr < 2; ++mr)
                #pragma unroll
                for (int nr = 0; nr < 2; ++nr)
                    acc[mr][nr] = __builtin_amdgcn_mfma_f32_16x16x32_bf16(afh[mr], bfh[nr], acc[mr][nr], 0, 0, 0);
        }
        __syncthreads();
    }
    int crow = (lane >> 4) * 4;
    int ccol = lane & 15;
    #pragma unroll
    for (int mr = 0; mr < 2; ++mr)
        #pragma unroll
        for (int nr = 0; nr < 2; ++nr) {
            int jc = j0 + wn * 32 + nr * 16 + ccol;
            #pragma unroll
            for (int jr = 0; jr < 4; ++jr) {
                int i = i0 + wm * 32 + mr * 16 + crow + jr;
                outS[(size_t)i * n + jc] = acc[mr][nr][jr];
            }
        }
}

// ---------------- kernel 3: stats = combine Sp+r+c -> S, P_alpha bf16 (permuted), col partials ----------------
__global__ __launch_bounds__(TPB) void stats_kernel(
    const float* __restrict__ Sp, const float* __restrict__ r, const float* __restrict__ c,
    float* __restrict__ S, u16* __restrict__ Palpha,
    float* __restrict__ pm, float* __restrict__ ps, int m, int n) {
    __shared__ float red[TPB];
    int tid = threadIdx.x;
    int col = tid * 4;
    size_t mn = (size_t)m * n;
    float4 cv = *(const float4*)(c + col);
    float v[4][4];
    #pragma unroll
    for (int rr = 0; rr < 4; ++rr) {
        int row = blockIdx.x * 4 + rr;
        size_t base = (size_t)row * n + col;
        float4 a0 = *(const float4*)(Sp + base);
        float4 a1 = *(const float4*)(Sp + mn + base);
        float4 a2 = *(const float4*)(Sp + 2 * mn + base);
        float4 a3 = *(const float4*)(Sp + 3 * mn + base);
        float rv = r[row];
        float4 o;
        o.x = a0.x + a1.x + a2.x + a3.x + rv + cv.x;
        o.y = a0.y + a1.y + a2.y + a3.y + rv + cv.y;
        o.z = a0.z + a1.z + a2.z + a3.z + rv + cv.z;
        o.w = a0.w + a1.w + a2.w + a3.w + rv + cv.w;
        *(float4*)(S + base) = o;
        v[rr][0] = o.x; v[rr][1] = o.y; v[rr][2] = o.z; v[rr][3] = o.w;
    }
    int pcol = (col & ~31) + pos32(col & 31);
    // row stats + P_alpha (rows fully inside this block)
    #pragma unroll
    for (int rr = 0; rr < 4; ++rr) {
        int row = blockIdx.x * 4 + rr;
        float lm = fmaxf(fmaxf(v[rr][0], v[rr][1]), fmaxf(v[rr][2], v[rr][3]));
        red[tid] = lm;
        __syncthreads();
        for (int s = TPB / 2; s > 0; s >>= 1) {
            if (tid < s) red[tid] = fmaxf(red[tid], red[tid + s]);
            __syncthreads();
        }
        float gm = red[0];
        __syncthreads();
        float e0 = __expf(v[rr][0] - gm), e1 = __expf(v[rr][1] - gm);
        float e2 = __expf(v[rr][2] - gm), e3 = __expf(v[rr][3] - gm);
        red[tid] = e0 + e1 + e2 + e3;
        __syncthreads();
        for (int s = TPB / 2; s > 0; s >>= 1) {
            if (tid < s) red[tid] += red[tid + s];
            __syncthreads();
        }
        float inv = 1.f / red[0];
        __syncthreads();
        u16x4 pa = {f2bf(e0 * inv), f2bf(e1 * inv), f2bf(e2 * inv), f2bf(e3 * inv)};
        *(u16x4*)(Palpha + (size_t)row * n + pcol) = pa;
    }
    // col partial stats (chunk = blockIdx.x covers 4 rows)
    #pragma unroll
    for (int e = 0; e < 4; ++e) {
        float cmx = fmaxf(fmaxf(v[0][e], v[1][e]), fmaxf(v[2][e], v[3][e]));
        float cs = __expf(v[0][e] - cmx) + __expf(v[1][e] - cmx) +
                   __expf(v[2][e] - cmx) + __expf(v[3][e] - cmx);
        pm[(size_t)blockIdx.x * n + col + e] = cmx;
        ps[(size_t)blockIdx.x * n + col + e] = cs;
    }
}

// ---------------- kernel 4: col merge (two-level; 16 cols x 16 groups per block) ----------------
__global__ __launch_bounds__(TPB) void col_merge(
    const float* __restrict__ pm, const float* __restrict__ ps,
    float* __restrict__ cmv, float* __restrict__ ics, int n, int chunks) {
    __shared__ float sm[TPB], ss[TPB];
    int colLocal = threadIdx.x & 15;
    int grp = threadIdx.x >> 4;
    int col = blockIdx.x * 16 + colLocal;
    int per = chunks / 16;
    float mx = -INFINITY, s = 0.f;
    for (int cc = grp * per; cc < (grp + 1) * per; ++cc) {
        float pmv = pm[(size_t)cc * n + col];
        float psv = ps[(size_t)cc * n + col];
        if (pmv <= mx) {
            s += psv * __expf(pmv - mx);
        } else {
            s = s * __expf(mx - pmv) + psv;
            mx = pmv;
        }
    }
    sm[threadIdx.x] = mx; ss[threadIdx.x] = s;
    __syncthreads();
    for (int st = 128; st >= 16; st >>= 1) {
        if (threadIdx.x < st) {
            float m1 = sm[threadIdx.x], s1 = ss[threadIdx.x];
            float m2 = sm[threadIdx.x + st], s2 = ss[threadIdx.x + st];
            float mo = fmaxf(m1, m2);
            ss[threadIdx.x] = s1 * __expf(m1 - mo) + s2 * __expf(m2 - mo);
            sm[threadIdx.x] = mo;
        }
        __syncthreads();
    }
    if (threadIdx.x < 16) {
        cmv[col] = sm[threadIdx.x];
        ics[col] = 1.f / ss[threadIdx.x];
    }
}

// ---------------- kernel 5: P_beta^T bf16 = transpose(exp(S - cm)*ics), perm on i ----------------
__global__ __launch_bounds__(TPB) void pbt_kernel(
    const float* __restrict__ S, const float* __restrict__ cm, const float* __restrict__ ics,
    u16* __restrict__ PbT, int m, int n) {
    __shared__ float t[64 * 65];
    int tid = threadIdx.x;
    int r0 = blockIdx.y * 64;  // i
    int c0 = blockIdx.x * 64;  // j
    #pragma unroll
    for (int it = 0; it < 4; ++it) {
        int rr = (tid >> 4) + it * 16;
        int cc = (tid & 15) * 4;
        float4 v = *(const float4*)(S + (size_t)(r0 + rr) * n + c0 + cc);
        t[(cc + 0) * 65 + rr] = v.x;
        t[(cc + 1) * 65 + rr] = v.y;
        t[(cc + 2) * 65 + rr] = v.z;
        t[(cc + 3) * 65 + rr] = v.w;
    }
    __syncthreads();
    #pragma unroll
    for (int it = 0; it < 2; ++it) {
        int id = tid + it * TPB;
        int jj = id >> 3;
        int s = id & 7;
        float mj = cm[c0 + jj];
        float scj = ics[c0 + jj];
        u16 outv[8];
        #pragma unroll
        for (int e = 0; e < 8; ++e) {
            int p = s * 8 + e;
            int iloc = 32 * (p >> 5) + ipos32(p & 31);
            outv[e] = f2bf(__expf(t[jj * 65 + iloc] - mj) * scj);
        }
        *(u16x4*)(PbT + (size_t)(c0 + jj) * m + r0 + s * 8) = *(u16x4*)&outv[0];
        *(u16x4*)(PbT + (size_t)(c0 + jj) * m + r0 + s * 8 + 4) = *(u16x4*)&outv[4];
    }
}

// ---------------- kernel 6: attn = two pure bf16 GEMMs (z=0: aalpha, z=1: abeta) ----------------
__global__ __launch_bounds__(TPB) void attn_mfma(
    const u16* __restrict__ Palpha, const u16* __restrict__ PbT,
    const u16* __restrict__ ucT, const u16* __restrict__ upT,
    float* __restrict__ aalpha, float* __restrict__ abeta,
    int m, int n, int d) {
    __shared__ u16 sA[4096];
    __shared__ u16 sB[4096];
    int tid = threadIdx.x;
    int lane = tid & 63, wave = tid >> 6;
    int wm = wave >> 1, wn = wave & 1;
    int lrow = lane & 15, g = lane >> 4;
    int i0 = blockIdx.y * 64, kc0 = blockIdx.x * 64;
    const u16* A; const u16* B; float* outp; int kT;
    if (blockIdx.z == 0) { A = Palpha; B = ucT; outp = aalpha; kT = n; }
    else                 { A = PbT;    B = upT; outp = abeta;  kT = m; }
    f32x4 acc[2][2];
    #pragma unroll
    for (int a = 0; a < 2; ++a)
        #pragma unroll
        for (int bq = 0; bq < 2; ++bq) acc[a][bq] = (f32x4){0.f, 0.f, 0.f, 0.f};

    for (int k0 = 0; k0 < kT; k0 += 64) {
        #pragma unroll
        for (int it = 0; it < 2; ++it) {
            int id = tid + it * TPB;
            int row = id >> 3, slot = id & 7;
            int boff = (row * 128 + slot * 16) ^ ((row & 7) << 4);
            *(int4*)((char*)sA + boff) = *(const int4*)(A + (size_t)(i0 + row) * kT + k0 + slot * 8);
            *(int4*)((char*)sB + boff) = *(const int4*)(B + (size_t)(kc0 + row) * kT + k0 + slot * 8);
        }
        __syncthreads();
        #pragma unroll
        for (int kk = 0; kk < 2; ++kk) {
            bf16x8 av[2], bv[2];
            #pragma unroll
            for (int mr = 0; mr < 2; ++mr) {
                int row = wm * 32 + mr * 16 + lrow;
                int boff = (row * 128 + kk * 64 + g * 16) ^ ((row & 7) << 4);
                av[mr] = *(const bf16x8*)((const char*)sA + boff);
            }
            #pragma unroll
            for (int nr = 0; nr < 2; ++nr) {
                int row = wn * 32 + nr * 16 + lrow;
                int boff = (row * 128 + kk * 64 + g * 16) ^ ((row & 7) << 4);
                bv[nr] = *(const bf16x8*)((const char*)sB + boff);
            }
            #pragma unroll
            for (int mr = 0; mr < 2; ++mr)
                #pragma unroll
                for (int nr = 0; nr < 2; ++nr)
                    acc[mr][nr] = __builtin_amdgcn_mfma_f32_16x16x32_bf16(av[mr], bv[nr], acc[mr][nr], 0, 0, 0);
        }
        __syncthreads();
    }
    int crow = (lane >> 4) * 4;
    int ccol = lane & 15;
    #pragma unroll
    for (int mr = 0; mr < 2; ++mr)
        #pragma unroll
        for (int nr = 0; nr < 2; ++nr) {
            int kc = kc0 + wn * 32 + nr * 16 + ccol;
            #pragma unroll
            for (int jr = 0; jr < 4; ++jr) {
                int i = i0 + wm * 32 + mr * 16 + crow + jr;
                outp[(size_t)i * d + kc] = acc[mr][nr][jr];
            }
        }
}

// ---------------- kernel 7: fused final dot, stage 1 ----------------
__global__ __launch_bounds__(TPB) void final_stage1(
    const float* __restrict__ u_p, const float* __restrict__ u_c,
    const float* __restrict__ aalpha, const float* __restrict__ abeta,
    const float* __restrict__ W, float* __restrict__ partials, int n, int d) {
    size_t total = (size_t)n * d / 4;
    float acc = 0.f;
    for (size_t q = (size_t)blockIdx.x * TPB + threadIdx.x; q < total;
         q += (size_t)gridDim.x * TPB) {
        size_t e = q * 4;
        int i = (int)(e / d);
        int k = (int)(e % d);
        size_t base = (size_t)i * d + k;
        float4 up = *(const float4*)(u_p + base);
        float4 aa = *(const float4*)(aalpha + base);
        float4 uc = *(const float4*)(u_c + base);
        float4 ab = *(const float4*)(abeta + base);
        const float* wr = W + (size_t)i * 4 * d;
        float4 w0 = *(const float4*)(wr + k);
        float4 w1 = *(const float4*)(wr + d + k);
        float4 w2 = *(const float4*)(wr + 2 * d + k);
        float4 w3 = *(const float4*)(wr + 3 * d + k);
        acc += up.x * w0.x + aa.x * (w1.x + up.x * w2.x) + uc.x * ab.x * w3.x;
        acc += up.y * w0.y + aa.y * (w1.y + up.y * w2.y) + uc.y * ab.y * w3.y;
        acc += up.z * w0.z + aa.z * (w1.z + up.z * w2.z) + uc.z * ab.z * w3.z;
        acc += up.w * w0.w + aa.w * (w1.w + up.w * w2.w) + uc.w * ab.w * w3.w;
    }
    __shared__ float red[TPB];
    red[threadIdx.x] = acc;
    __syncthreads();
    for (int s = TPB / 2; s > 0; s >>= 1) {
        if (threadIdx.x < s) red[threadIdx.x] += red[threadIdx.x + s];
        __syncthreads();
    }
    if (threadIdx.x == 0) partials[blockIdx.x] = red[0];
}

// ---------------- kernel 8: stage 2 ----------------
__global__ __launch_bounds__(TPB) void final_stage2(
    const float* __restrict__ partials, int np, const float* __restrict__ bias,
    float* __restrict__ out) {
    double acc = 0.0;
    for (int t = threadIdx.x; t < np; t += TPB) acc += (double)partials[t];
    __shared__ double red[TPB];
    red[threadIdx.x] = acc;
    __syncthreads();
    for (int s = TPB / 2; s > 0; s >>= 1) {
        if (threadIdx.x < s) red[threadIdx.x] += red[threadIdx.x + s];
        __syncthreads();
    }
    if (threadIdx.x == 0) {
        double v = red[0] + (double)bias[0];
        out[0] = (float)(v > 0.0 ? v : 0.0);
    }
}

extern "C" void kernel_launch(void* const* d_in, const int* in_sizes, int n_in,
                              void* d_out, int out_size, void* d_ws, size_t ws_size,
                              hipStream_t stream) {
    const float* u_p = (const float*)d_in[0];
    const float* u_c = (const float*)d_in[1];
    const float* w_a = (const float*)d_in[2];
    const float* ffn_w = (const float*)d_in[3];
    const float* ffn_b = (const float*)d_in[4];
    float* out = (float*)d_out;

    int d = in_sizes[2] / 3;   // 2048
    int m = in_sizes[0] / d;   // 1024
    int n = in_sizes[1] / d;   // 1024  (== m; attn kernel assumes m == n)
    const int NBLK_FINAL = 2048;
    const int KSPLIT = 4;
    int chunks = m / 4;        // 256 col-stat chunks

    size_t md = (size_t)m * d, nd = (size_t)n * d, mn = (size_t)m * n;

    float* ws = (float*)d_ws;
    float* r = ws;                       // m
    float* c = r + m;                    // n
    float* cm = c + n;                   // n
    float* inv_cs = cm + n;              // n
    float* pm = inv_cs + n;              // chunks*n
    float* ps = pm + (size_t)chunks * n; // chunks*n
    float* partials = ps + (size_t)chunks * n;   // NBLK_FINAL
    float* S = partials + NBLK_FINAL;    // mn
    float* Sp = S + mn;                  // KSPLIT*mn
    float* aalpha = Sp + (size_t)KSPLIT * mn;    // md
    float* abeta = aalpha + md;          // nd
    u16* Palpha = (u16*)(abeta + nd);    // mn
    u16* PbT = Palpha + mn;              // mn
    u16* upw3 = PbT + mn;                // md
    u16* ucb = upw3 + md;                // nd
    u16* ucT = ucb + nd;                 // nd
    u16* upT = ucT + nd;                 // md

    // prep: transposes + convert + bias in one launch
    int nTc = (d / 64) * (n / 64);   // 512
    int nTp = (d / 64) * (m / 64);   // 512
    int nCv = 256;
    int nBs = (m + n) / 8;           // 256
    prep_kernel<<<nTc + nTp + nCv + nBs, TPB, 0, stream>>>(
        u_p, u_c, w_a, upw3, ucb, ucT, upT, r, c, m, n, d, nTc, nTp, nCv, nBs);

    // S partials (no atomics)
    dim3 gS(n / 64, m / 64, KSPLIT);
    gemmS_mfma<<<gS, TPB, 0, stream>>>(upw3, ucb, Sp, m, n, d, KSPLIT);

    // combine + row softmax -> P_alpha + col partial stats
    stats_kernel<<<m / 4, TPB, 0, stream>>>(Sp, r, c, S, Palpha, pm, ps, m, n);

    // col merge
    col_merge<<<n / 16, TPB, 0, stream>>>(pm, ps, cm, inv_cs, n, chunks);

    // P_beta^T
    dim3 gP(n / 64, m / 64);
    pbt_kernel<<<gP, TPB, 0, stream>>>(S, cm, inv_cs, PbT, m, n);

    // attn: two pure bf16 GEMMs
    dim3 gA(d / 64, m / 64, 2);
    attn_mfma<<<gA, TPB, 0, stream>>>(Palpha, PbT, ucT, upT, aalpha, abeta, m, n, d);

    final_stage1<<<NBLK_FINAL, TPB, 0, stream>>>(u_p, u_c, aalpha, abeta, ffn_w,
                                                 partials, n, d);
    final_stage2<<<1, TPB, 0, stream>>>(partials, NBLK_FINAL, ffn_b, out);

    (void)out_size; (void)ws_size; (void)n_in;
}

// Round 9
// 82.228 us; speedup vs baseline: 2.2537x; 1.0079x over previous
//
#include <hip/hip_runtime.h>
#include <math.h>

#define TPB 256

typedef unsigned short u16;
typedef short bf16x8 __attribute__((ext_vector_type(8)));
typedef unsigned short u16x4 __attribute__((ext_vector_type(4)));
typedef float f32x4 __attribute__((ext_vector_type(4)));

__device__ __forceinline__ u16 f2bf(float x) {
    unsigned u = __float_as_uint(x);
    unsigned r = u + 0x7fffu + ((u >> 16) & 1u);
    return (u16)(r >> 16);
}
__device__ __forceinline__ float bf2f(u16 h) {
    return __uint_as_float(((unsigned)h) << 16);
}
// k-permutation within a 32-wide chunk (half-split fragment layout). Applied
// consistently to BOTH GEMM operands -> correctness independent of HW k-order.
// 4-aligned groups remain contiguous: pos32(4q+e) = pos32(4q)+e.
__device__ __forceinline__ int pos32(int kk) {
    return ((kk >> 2) & 3) * 8 + (kk >> 4) * 4 + (kk & 3);
}
__device__ __forceinline__ int ipos32(int p5) {
    return 16 * ((p5 >> 2) & 1) + 4 * (p5 >> 3) + (p5 & 3);
}

// ---------------- kernel 1: prep = (transpose+convert fused) + bias ----------------
__global__ __launch_bounds__(TPB) void prep_kernel(
    const float* __restrict__ up, const float* __restrict__ uc,
    const float* __restrict__ wa,
    u16* __restrict__ upw3, u16* __restrict__ ucb,
    u16* __restrict__ ucT, u16* __restrict__ upT,
    float* __restrict__ r, float* __restrict__ c,
    int m, int n, int d, int nTc, int nTp) {
    __shared__ float t[64 * 65];
    int b = blockIdx.x;
    int tid = threadIdx.x;

    if (b < nTc + nTp) {
        // ---- tile role: one 64x64 tile -> transposed bf16 (perm on row idx)
        //                                 + row-major bf16 (perm on k idx) ----
        const float* src; u16* dstT; u16* dstR; int rows; int tt; int isUp;
        if (b < nTc) { src = uc; dstT = ucT; dstR = ucb;  rows = n; tt = b;       isUp = 0; }
        else         { src = up; dstT = upT; dstR = upw3; rows = m; tt = b - nTc; isUp = 1; }
        int ntx = d / 64;
        int c0 = (tt % ntx) * 64;   // k-range
        int r0 = (tt / ntx) * 64;   // row-range
        #pragma unroll
        for (int it = 0; it < 4; ++it) {
            int rr = (tid >> 4) + it * 16;
            int cc = (tid & 15) * 4;
            float4 v = *(const float4*)(src + (size_t)(r0 + rr) * d + c0 + cc);
            t[(cc + 0) * 65 + rr] = v.x;
            t[(cc + 1) * 65 + rr] = v.y;
            t[(cc + 2) * 65 + rr] = v.z;
            t[(cc + 3) * 65 + rr] = v.w;
        }
        __syncthreads();
        // phase 2: transposed output dstT[d][rows], row-idx permuted
        #pragma unroll
        for (int it = 0; it < 2; ++it) {
            int id = tid + it * TPB;
            int kc = id >> 3;
            int s = id & 7;
            u16 outv[8];
            #pragma unroll
            for (int e = 0; e < 8; ++e) {
                int p = s * 8 + e;
                int jloc = 32 * (p >> 5) + ipos32(p & 31);
                outv[e] = f2bf(t[kc * 65 + jloc]);
            }
            *(u16x4*)(dstT + (size_t)(c0 + kc) * rows + r0 + s * 8) = *(u16x4*)&outv[0];
            *(u16x4*)(dstT + (size_t)(c0 + kc) * rows + r0 + s * 8 + 4) = *(u16x4*)&outv[4];
        }
        // phase 3: row-major converted output dstR[rows][d], k permuted
        {
            int rr = tid >> 2;               // 0..63
            int cbase = (tid & 3) * 16;      // 0,16,32,48
            #pragma unroll
            for (int grp = 0; grp < 4; ++grp) {
                int k = cbase + grp * 4;
                u16x4 o;
                #pragma unroll
                for (int e = 0; e < 4; ++e) {
                    float val = t[(k + e) * 65 + rr];
                    if (isUp) val *= wa[2 * d + c0 + k + e];
                    o[e] = f2bf(val);
                }
                int K = c0 + k;
                int p = (K & ~31) + pos32(K & 31);
                *(u16x4*)(dstR + (size_t)(r0 + rr) * d + p) = o;
            }
        }
    } else {
        // ---- bias role: r[i]=u_p[i]·w1, c[j]=u_c[j]·w2 ; 8 rows/block ----
        int bb = b - nTc - nTp;
        int lane = tid & 63, wave = tid >> 6;
        for (int q = wave; q < 8; q += 4) {
            int row = bb * 8 + q;
            const float* src; const float* w; float* dst;
            if (row < m) { src = up + (size_t)row * d;       w = wa;     dst = r + row; }
            else         { src = uc + (size_t)(row - m) * d; w = wa + d; dst = c + (row - m); }
            float acc = 0.f;
            for (int k4 = lane; k4 < d / 4; k4 += 64) {
                float4 a = ((const float4*)src)[k4];
                float4 ww = ((const float4*)w)[k4];
                acc += a.x * ww.x + a.y * ww.y + a.z * ww.z + a.w * ww.w;
            }
            #pragma unroll
            for (int off = 32; off > 0; off >>= 1) acc += __shfl_down(acc, off);
            if (lane == 0) *dst = acc;
        }
    }
}

// ---------------- kernel 2: gemmS partials, 128x64 tile: Sp[z] = upw3 @ ucb^T ----------------
__global__ __launch_bounds__(TPB) void gemmS_mfma(
    const u16* __restrict__ Ah, const u16* __restrict__ Bh,
    float* __restrict__ Sp, int m, int n, int d, int ksplit) {
    __shared__ u16 sA[128 * 64];  // 16 KB
    __shared__ u16 sB[64 * 64];   // 8 KB
    int tid = threadIdx.x;
    int lane = tid & 63, wave = tid >> 6;
    int wm = wave >> 1, wn = wave & 1;
    int lrow = lane & 15, g = lane >> 4;
    int i0 = blockIdx.y * 128, j0 = blockIdx.x * 64;
    int kchunk = d / ksplit;
    int kbeg = blockIdx.z * kchunk;
    float* outS = Sp + (size_t)blockIdx.z * m * n;
    f32x4 acc[4][2];
    #pragma unroll
    for (int a = 0; a < 4; ++a)
        #pragma unroll
        for (int bq = 0; bq < 2; ++bq) acc[a][bq] = (f32x4){0.f, 0.f, 0.f, 0.f};

    for (int k0 = kbeg; k0 < kbeg + kchunk; k0 += 64) {
        #pragma unroll
        for (int it = 0; it < 4; ++it) {
            int id = tid + it * TPB;
            int row = id >> 3, slot = id & 7;
            int boff = (row * 128 + slot * 16) ^ ((row & 7) << 4);
            *(int4*)((char*)sA + boff) = *(const int4*)(Ah + (size_t)(i0 + row) * d + k0 + slot * 8);
        }
        #pragma unroll
        for (int it = 0; it < 2; ++it) {
            int id = tid + it * TPB;
            int row = id >> 3, slot = id & 7;
            int boff = (row * 128 + slot * 16) ^ ((row & 7) << 4);
            *(int4*)((char*)sB + boff) = *(const int4*)(Bh + (size_t)(j0 + row) * d + k0 + slot * 8);
        }
        __syncthreads();
        #pragma unroll
        for (int kk = 0; kk < 2; ++kk) {
            bf16x8 af[4], bf[2];
            #pragma unroll
            for (int mr = 0; mr < 4; ++mr) {
                int row = wm * 64 + mr * 16 + lrow;
                int boff = (row * 128 + kk * 64 + g * 16) ^ ((row & 7) << 4);
                af[mr] = *(const bf16x8*)((const char*)sA + boff);
            }
            #pragma unroll
            for (int nr = 0; nr < 2; ++nr) {
                int row = wn * 32 + nr * 16 + lrow;
                int boff = (row * 128 + kk * 64 + g * 16) ^ ((row & 7) << 4);
                bf[nr] = *(const bf16x8*)((const char*)sB + boff);
            }
            #pragma unroll
            for (int mr = 0; mr < 4; ++mr)
                #pragma unroll
                for (int nr = 0; nr < 2; ++nr)
                    acc[mr][nr] = __builtin_amdgcn_mfma_f32_16x16x32_bf16(af[mr], bf[nr], acc[mr][nr], 0, 0, 0);
        }
        __syncthreads();
    }
    int crow = (lane >> 4) * 4;
    int ccol = lane & 15;
    #pragma unroll
    for (int mr = 0; mr < 4; ++mr)
        #pragma unroll
        for (int nr = 0; nr < 2; ++nr) {
            int jc = j0 + wn * 32 + nr * 16 + ccol;
            #pragma unroll
            for (int jr = 0; jr < 4; ++jr) {
                int i = i0 + wm * 64 + mr * 16 + crow + jr;
                outS[(size_t)i * n + jc] = acc[mr][nr][jr];
            }
        }
}

// ---------------- kernel 3: stats = combine Sp+r+c -> S, P_alpha bf16, col partials ----------------
__global__ __launch_bounds__(TPB) void stats_kernel(
    const float* __restrict__ Sp, const float* __restrict__ r, const float* __restrict__ c,
    float* __restrict__ S, u16* __restrict__ Palpha,
    float* __restrict__ pm, float* __restrict__ ps, int m, int n) {
    __shared__ float red[TPB];
    int tid = threadIdx.x;
    int col = tid * 4;
    size_t mn = (size_t)m * n;
    float4 cv = *(const float4*)(c + col);
    float v[4][4];
    #pragma unroll
    for (int rr = 0; rr < 4; ++rr) {
        int row = blockIdx.x * 4 + rr;
        size_t base = (size_t)row * n + col;
        float4 a0 = *(const float4*)(Sp + base);
        float4 a1 = *(const float4*)(Sp + mn + base);
        float4 a2 = *(const float4*)(Sp + 2 * mn + base);
        float4 a3 = *(const float4*)(Sp + 3 * mn + base);
        float rv = r[row];
        float4 o;
        o.x = a0.x + a1.x + a2.x + a3.x + rv + cv.x;
        o.y = a0.y + a1.y + a2.y + a3.y + rv + cv.y;
        o.z = a0.z + a1.z + a2.z + a3.z + rv + cv.z;
        o.w = a0.w + a1.w + a2.w + a3.w + rv + cv.w;
        *(float4*)(S + base) = o;
        v[rr][0] = o.x; v[rr][1] = o.y; v[rr][2] = o.z; v[rr][3] = o.w;
    }
    int pcol = (col & ~31) + pos32(col & 31);
    #pragma unroll
    for (int rr = 0; rr < 4; ++rr) {
        int row = blockIdx.x * 4 + rr;
        float lm = fmaxf(fmaxf(v[rr][0], v[rr][1]), fmaxf(v[rr][2], v[rr][3]));
        red[tid] = lm;
        __syncthreads();
        for (int s = TPB / 2; s > 0; s >>= 1) {
            if (tid < s) red[tid] = fmaxf(red[tid], red[tid + s]);
            __syncthreads();
        }
        float gm = red[0];
        __syncthreads();
        float e0 = __expf(v[rr][0] - gm), e1 = __expf(v[rr][1] - gm);
        float e2 = __expf(v[rr][2] - gm), e3 = __expf(v[rr][3] - gm);
        red[tid] = e0 + e1 + e2 + e3;
        __syncthreads();
        for (int s = TPB / 2; s > 0; s >>= 1) {
            if (tid < s) red[tid] += red[tid + s];
            __syncthreads();
        }
        float inv = 1.f / red[0];
        __syncthreads();
        u16x4 pa = {f2bf(e0 * inv), f2bf(e1 * inv), f2bf(e2 * inv), f2bf(e3 * inv)};
        *(u16x4*)(Palpha + (size_t)row * n + pcol) = pa;
    }
    #pragma unroll
    for (int e = 0; e < 4; ++e) {
        float cmx = fmaxf(fmaxf(v[0][e], v[1][e]), fmaxf(v[2][e], v[3][e]));
        float cs = __expf(v[0][e] - cmx) + __expf(v[1][e] - cmx) +
                   __expf(v[2][e] - cmx) + __expf(v[3][e] - cmx);
        pm[(size_t)blockIdx.x * n + col + e] = cmx;
        ps[(size_t)blockIdx.x * n + col + e] = cs;
    }
}

// ---------------- kernel 4: col merge ----------------
__global__ __launch_bounds__(TPB) void col_merge(
    const float* __restrict__ pm, const float* __restrict__ ps,
    float* __restrict__ cmv, float* __restrict__ ics, int n, int chunks) {
    __shared__ float sm[TPB], ss[TPB];
    int colLocal = threadIdx.x & 15;
    int grp = threadIdx.x >> 4;
    int col = blockIdx.x * 16 + colLocal;
    int per = chunks / 16;
    float mx = -INFINITY, s = 0.f;
    for (int cc = grp * per; cc < (grp + 1) * per; ++cc) {
        float pmv = pm[(size_t)cc * n + col];
        float psv = ps[(size_t)cc * n + col];
        if (pmv <= mx) {
            s += psv * __expf(pmv - mx);
        } else {
            s = s * __expf(mx - pmv) + psv;
            mx = pmv;
        }
    }
    sm[threadIdx.x] = mx; ss[threadIdx.x] = s;
    __syncthreads();
    for (int st = 128; st >= 16; st >>= 1) {
        if (threadIdx.x < st) {
            float m1 = sm[threadIdx.x], s1 = ss[threadIdx.x];
            float m2 = sm[threadIdx.x + st], s2 = ss[threadIdx.x + st];
            float mo = fmaxf(m1, m2);
            ss[threadIdx.x] = s1 * __expf(m1 - mo) + s2 * __expf(m2 - mo);
            sm[threadIdx.x] = mo;
        }
        __syncthreads();
    }
    if (threadIdx.x < 16) {
        cmv[col] = sm[threadIdx.x];
        ics[col] = 1.f / ss[threadIdx.x];
    }
}

// ---------------- kernel 5: P_beta^T bf16 = transpose(exp(S - cm)*ics), perm on i ----------------
__global__ __launch_bounds__(TPB) void pbt_kernel(
    const float* __restrict__ S, const float* __restrict__ cm, const float* __restrict__ ics,
    u16* __restrict__ PbT, int m, int n) {
    __shared__ float t[64 * 65];
    int tid = threadIdx.x;
    int r0 = blockIdx.y * 64;
    int c0 = blockIdx.x * 64;
    #pragma unroll
    for (int it = 0; it < 4; ++it) {
        int rr = (tid >> 4) + it * 16;
        int cc = (tid & 15) * 4;
        float4 v = *(const float4*)(S + (size_t)(r0 + rr) * n + c0 + cc);
        t[(cc + 0) * 65 + rr] = v.x;
        t[(cc + 1) * 65 + rr] = v.y;
        t[(cc + 2) * 65 + rr] = v.z;
        t[(cc + 3) * 65 + rr] = v.w;
    }
    __syncthreads();
    #pragma unroll
    for (int it = 0; it < 2; ++it) {
        int id = tid + it * TPB;
        int jj = id >> 3;
        int s = id & 7;
        float mj = cm[c0 + jj];
        float scj = ics[c0 + jj];
        u16 outv[8];
        #pragma unroll
        for (int e = 0; e < 8; ++e) {
            int p = s * 8 + e;
            int iloc = 32 * (p >> 5) + ipos32(p & 31);
            outv[e] = f2bf(__expf(t[jj * 65 + iloc] - mj) * scj);
        }
        *(u16x4*)(PbT + (size_t)(c0 + jj) * m + r0 + s * 8) = *(u16x4*)&outv[0];
        *(u16x4*)(PbT + (size_t)(c0 + jj) * m + r0 + s * 8 + 4) = *(u16x4*)&outv[4];
    }
}

// ---------------- kernel 6: attn = two pure bf16 GEMMs, 128x64 tile, bf16 out ----------------
__global__ __launch_bounds__(TPB) void attn_mfma(
    const u16* __restrict__ Palpha, const u16* __restrict__ PbT,
    const u16* __restrict__ ucT, const u16* __restrict__ upT,
    u16* __restrict__ aalpha, u16* __restrict__ abeta,
    int m, int n, int d) {
    __shared__ u16 sA[128 * 64];
    __shared__ u16 sB[64 * 64];
    int tid = threadIdx.x;
    int lane = tid & 63, wave = tid >> 6;
    int wm = wave >> 1, wn = wave & 1;
    int lrow = lane & 15, g = lane >> 4;
    int i0 = blockIdx.y * 128, kc0 = blockIdx.x * 64;
    const u16* A; const u16* B; u16* outp; int kT;
    if (blockIdx.z == 0) { A = Palpha; B = ucT; outp = aalpha; kT = n; }
    else                 { A = PbT;    B = upT; outp = abeta;  kT = m; }
    f32x4 acc[4][2];
    #pragma unroll
    for (int a = 0; a < 4; ++a)
        #pragma unroll
        for (int bq = 0; bq < 2; ++bq) acc[a][bq] = (f32x4){0.f, 0.f, 0.f, 0.f};

    for (int k0 = 0; k0 < kT; k0 += 64) {
        #pragma unroll
        for (int it = 0; it < 4; ++it) {
            int id = tid + it * TPB;
            int row = id >> 3, slot = id & 7;
            int boff = (row * 128 + slot * 16) ^ ((row & 7) << 4);
            *(int4*)((char*)sA + boff) = *(const int4*)(A + (size_t)(i0 + row) * kT + k0 + slot * 8);
        }
        #pragma unroll
        for (int it = 0; it < 2; ++it) {
            int id = tid + it * TPB;
            int row = id >> 3, slot = id & 7;
            int boff = (row * 128 + slot * 16) ^ ((row & 7) << 4);
            *(int4*)((char*)sB + boff) = *(const int4*)(B + (size_t)(kc0 + row) * kT + k0 + slot * 8);
        }
        __syncthreads();
        #pragma unroll
        for (int kk = 0; kk < 2; ++kk) {
            bf16x8 af[4], bf[2];
            #pragma unroll
            for (int mr = 0; mr < 4; ++mr) {
                int row = wm * 64 + mr * 16 + lrow;
                int boff = (row * 128 + kk * 64 + g * 16) ^ ((row & 7) << 4);
                af[mr] = *(const bf16x8*)((const char*)sA + boff);
            }
            #pragma unroll
            for (int nr = 0; nr < 2; ++nr) {
                int row = wn * 32 + nr * 16 + lrow;
                int boff = (row * 128 + kk * 64 + g * 16) ^ ((row & 7) << 4);
                bf[nr] = *(const bf16x8*)((const char*)sB + boff);
            }
            #pragma unroll
            for (int mr = 0; mr < 4; ++mr)
                #pragma unroll
                for (int nr = 0; nr < 2; ++nr)
                    acc[mr][nr] = __builtin_amdgcn_mfma_f32_16x16x32_bf16(af[mr], bf[nr], acc[mr][nr], 0, 0, 0);
        }
        __syncthreads();
    }
    int crow = (lane >> 4) * 4;
    int ccol = lane & 15;
    #pragma unroll
    for (int mr = 0; mr < 4; ++mr)
        #pragma unroll
        for (int nr = 0; nr < 2; ++nr) {
            int kc = kc0 + wn * 32 + nr * 16 + ccol;
            #pragma unroll
            for (int jr = 0; jr < 4; ++jr) {
                int i = i0 + wm * 64 + mr * 16 + crow + jr;
                outp[(size_t)i * d + kc] = f2bf(acc[mr][nr][jr]);
            }
        }
}

// ---------------- kernel 7: fused final dot, stage 1 (aa/ab in bf16) ----------------
__global__ __launch_bounds__(TPB) void final_stage1(
    const float* __restrict__ u_p, const float* __restrict__ u_c,
    const u16* __restrict__ aalpha, const u16* __restrict__ abeta,
    const float* __restrict__ W, float* __restrict__ partials, int n, int d) {
    size_t total = (size_t)n * d / 4;
    float acc = 0.f;
    for (size_t q = (size_t)blockIdx.x * TPB + threadIdx.x; q < total;
         q += (size_t)gridDim.x * TPB) {
        size_t e = q * 4;
        int i = (int)(e / d);
        int k = (int)(e % d);
        size_t base = (size_t)i * d + k;
        float4 up = *(const float4*)(u_p + base);
        float4 uc = *(const float4*)(u_c + base);
        u16x4 aah = *(const u16x4*)(aalpha + base);
        u16x4 abh = *(const u16x4*)(abeta + base);
        float4 aa = {bf2f(aah[0]), bf2f(aah[1]), bf2f(aah[2]), bf2f(aah[3])};
        float4 ab = {bf2f(abh[0]), bf2f(abh[1]), bf2f(abh[2]), bf2f(abh[3])};
        const float* wr = W + (size_t)i * 4 * d;
        float4 w0 = *(const float4*)(wr + k);
        float4 w1 = *(const float4*)(wr + d + k);
        float4 w2 = *(const float4*)(wr + 2 * d + k);
        float4 w3 = *(const float4*)(wr + 3 * d + k);
        acc += up.x * w0.x + aa.x * (w1.x + up.x * w2.x) + uc.x * ab.x * w3.x;
        acc += up.y * w0.y + aa.y * (w1.y + up.y * w2.y) + uc.y * ab.y * w3.y;
        acc += up.z * w0.z + aa.z * (w1.z + up.z * w2.z) + uc.z * ab.z * w3.z;
        acc += up.w * w0.w + aa.w * (w1.w + up.w * w2.w) + uc.w * ab.w * w3.w;
    }
    __shared__ float red[TPB];
    red[threadIdx.x] = acc;
    __syncthreads();
    for (int s = TPB / 2; s > 0; s >>= 1) {
        if (threadIdx.x < s) red[threadIdx.x] += red[threadIdx.x + s];
        __syncthreads();
    }
    if (threadIdx.x == 0) partials[blockIdx.x] = red[0];
}

// ---------------- kernel 8: stage 2 ----------------
__global__ __launch_bounds__(TPB) void final_stage2(
    const float* __restrict__ partials, int np, const float* __restrict__ bias,
    float* __restrict__ out) {
    double acc = 0.0;
    for (int t = threadIdx.x; t < np; t += TPB) acc += (double)partials[t];
    __shared__ double red[TPB];
    red[threadIdx.x] = acc;
    __syncthreads();
    for (int s = TPB / 2; s > 0; s >>= 1) {
        if (threadIdx.x < s) red[threadIdx.x] += red[threadIdx.x + s];
        __syncthreads();
    }
    if (threadIdx.x == 0) {
        double v = red[0] + (double)bias[0];
        out[0] = (float)(v > 0.0 ? v : 0.0);
    }
}

extern "C" void kernel_launch(void* const* d_in, const int* in_sizes, int n_in,
                              void* d_out, int out_size, void* d_ws, size_t ws_size,
                              hipStream_t stream) {
    const float* u_p = (const float*)d_in[0];
    const float* u_c = (const float*)d_in[1];
    const float* w_a = (const float*)d_in[2];
    const float* ffn_w = (const float*)d_in[3];
    const float* ffn_b = (const float*)d_in[4];
    float* out = (float*)d_out;

    int d = in_sizes[2] / 3;   // 2048
    int m = in_sizes[0] / d;   // 1024
    int n = in_sizes[1] / d;   // 1024  (assumes m == n)
    const int NBLK_FINAL = 2048;
    const int KSPLIT = 4;
    int chunks = m / 4;        // 256 col-stat chunks

    size_t md = (size_t)m * d, nd = (size_t)n * d, mn = (size_t)m * n;

    float* ws = (float*)d_ws;
    float* r = ws;                       // m
    float* c = r + m;                    // n
    float* cm = c + n;                   // n
    float* inv_cs = cm + n;              // n
    float* pm = inv_cs + n;              // chunks*n
    float* ps = pm + (size_t)chunks * n; // chunks*n
    float* partials = ps + (size_t)chunks * n;   // NBLK_FINAL
    float* S = partials + NBLK_FINAL;    // mn
    float* Sp = S + mn;                  // KSPLIT*mn
    u16* aalpha = (u16*)(Sp + (size_t)KSPLIT * mn);  // md u16
    u16* abeta = aalpha + md;            // nd u16
    u16* Palpha = abeta + nd;            // mn u16
    u16* PbT = Palpha + mn;              // mn u16
    u16* upw3 = PbT + mn;                // md
    u16* ucb = upw3 + md;                // nd
    u16* ucT = ucb + nd;                 // nd
    u16* upT = ucT + nd;                 // md

    // prep: fused transpose+convert tiles + bias
    int nTc = (d / 64) * (n / 64);   // 512
    int nTp = (d / 64) * (m / 64);   // 512
    int nBs = (m + n) / 8;           // 256
    prep_kernel<<<nTc + nTp + nBs, TPB, 0, stream>>>(
        u_p, u_c, w_a, upw3, ucb, ucT, upT, r, c, m, n, d, nTc, nTp);

    // S partials (128x64 tiles, no atomics)
    dim3 gS(n / 64, m / 128, KSPLIT);
    gemmS_mfma<<<gS, TPB, 0, stream>>>(upw3, ucb, Sp, m, n, d, KSPLIT);

    // combine + row softmax -> P_alpha + col partial stats
    stats_kernel<<<m / 4, TPB, 0, stream>>>(Sp, r, c, S, Palpha, pm, ps, m, n);

    // col merge
    col_merge<<<n / 16, TPB, 0, stream>>>(pm, ps, cm, inv_cs, n, chunks);

    // P_beta^T
    dim3 gP(n / 64, m / 64);
    pbt_kernel<<<gP, TPB, 0, stream>>>(S, cm, inv_cs, PbT, m, n);

    // attn: two pure bf16 GEMMs (128x64 tiles)
    dim3 gA(d / 64, m / 128, 2);
    attn_mfma<<<gA, TPB, 0, stream>>>(Palpha, PbT, ucT, upT, aalpha, abeta, m, n, d);

    final_stage1<<<NBLK_FINAL, TPB, 0, stream>>>(u_p, u_c, aalpha, abeta, ffn_w,
                                                 partials, n, d);
    final_stage2<<<1, TPB, 0, stream>>>(partials, NBLK_FINAL, ffn_b, out);

    (void)out_size; (void)ws_size; (void)n_in;
}

// Round 10
// 65.307 us; speedup vs baseline: 2.8377x; 1.2591x over previous
//
#include <hip/hip_runtime.h>
#include <math.h>

#define TPB 256

typedef unsigned short u16;
typedef short bf16x8 __attribute__((ext_vector_type(8)));
typedef unsigned short u16x4 __attribute__((ext_vector_type(4)));
typedef float f32x4 __attribute__((ext_vector_type(4)));

__device__ __forceinline__ u16 f2bf(float x) {
    unsigned u = __float_as_uint(x);
    unsigned r = u + 0x7fffu + ((u >> 16) & 1u);
    return (u16)(r >> 16);
}
__device__ __forceinline__ float bf2f(u16 h) {
    return __uint_as_float(((unsigned)h) << 16);
}
// k-permutation within a 32-wide chunk (half-split fragment layout). Applied
// consistently to BOTH GEMM operands -> correctness independent of HW k-order.
// 4-aligned groups stay contiguous: pos32(4q+e) = pos32(4q)+e.
__device__ __forceinline__ int pos32(int kk) {
    return ((kk >> 2) & 3) * 8 + (kk >> 4) * 4 + (kk & 3);
}
__device__ __forceinline__ int ipos32(int p5) {   // inverse of pos32
    return 16 * ((p5 >> 2) & 1) + 4 * (p5 >> 3) + (p5 & 3);
}

// ---------------- kernel 1: prep = transpose+convert+bias-partials per 64x64 tile ----------------
__global__ __launch_bounds__(TPB) void prep_kernel(
    const float* __restrict__ up, const float* __restrict__ uc,
    const float* __restrict__ wa,
    u16* __restrict__ upw3, u16* __restrict__ ucb,
    u16* __restrict__ ucT, u16* __restrict__ upT,
    float* __restrict__ rpart, float* __restrict__ cpart,
    float* __restrict__ zbuf,  // rowsum||colsum, 2*m floats, zeroed here
    int m, int n, int d, int nTc) {
    __shared__ float t[64 * 65];
    int b = blockIdx.x;
    int tid = threadIdx.x;

    if (b < 8) {  // zero rowsum/colsum for stats2's atomics (consumers launch later)
        int idx = b * TPB + tid;
        if (idx < 2 * m) zbuf[idx] = 0.f;
    }

    const float* src; u16* dstT; u16* dstR; float* bpart; int rows; int tt; int isUp;
    if (b < nTc) { src = uc; dstT = ucT; dstR = ucb;  bpart = cpart; rows = n; tt = b;       isUp = 0; }
    else         { src = up; dstT = upT; dstR = upw3; bpart = rpart; rows = m; tt = b - nTc; isUp = 1; }
    int ntx = d / 64;
    int c0 = (tt % ntx) * 64;   // k-range
    int r0 = (tt / ntx) * 64;   // row-range

    // load tile into LDS transposed: t[k][row]
    #pragma unroll
    for (int it = 0; it < 4; ++it) {
        int rr = (tid >> 4) + it * 16;
        int cc = (tid & 15) * 4;
        float4 v = *(const float4*)(src + (size_t)(r0 + rr) * d + c0 + cc);
        t[(cc + 0) * 65 + rr] = v.x;
        t[(cc + 1) * 65 + rr] = v.y;
        t[(cc + 2) * 65 + rr] = v.z;
        t[(cc + 3) * 65 + rr] = v.w;
    }
    __syncthreads();
    // phase 2: transposed output dstT[d][rows], row-idx permuted
    #pragma unroll
    for (int it = 0; it < 2; ++it) {
        int id = tid + it * TPB;
        int kc = id >> 3;
        int s = id & 7;
        u16 outv[8];
        #pragma unroll
        for (int e = 0; e < 8; ++e) {
            int p = s * 8 + e;
            int jloc = 32 * (p >> 5) + ipos32(p & 31);
            outv[e] = f2bf(t[kc * 65 + jloc]);
        }
        *(u16x4*)(dstT + (size_t)(c0 + kc) * rows + r0 + s * 8) = *(u16x4*)&outv[0];
        *(u16x4*)(dstT + (size_t)(c0 + kc) * rows + r0 + s * 8 + 4) = *(u16x4*)&outv[4];
    }
    // phase 3: row-major converted output dstR[rows][d], k permuted
    {
        int rr = tid >> 2;
        int cbase = (tid & 3) * 16;
        #pragma unroll
        for (int grp = 0; grp < 4; ++grp) {
            int k = cbase + grp * 4;
            u16x4 o;
            #pragma unroll
            for (int e = 0; e < 4; ++e) {
                float val = t[(k + e) * 65 + rr];
                if (isUp) val *= wa[2 * d + c0 + k + e];
                o[e] = f2bf(val);
            }
            int K = c0 + k;
            int p = (K & ~31) + pos32(K & 31);
            *(u16x4*)(dstR + (size_t)(r0 + rr) * d + p) = o;
        }
    }
    // phase 4: bias partial dots: bpart[kchunk][row] = sum_k tile[row,k]*w{1,2}[k]
    {
        int rr = tid >> 2;
        int kseg = tid & 3;
        const float* w = wa + (isUp ? 0 : d) + c0;
        float acc = 0.f;
        #pragma unroll
        for (int kk = 0; kk < 16; ++kk) {
            int k = kseg * 16 + kk;
            acc += t[k * 65 + rr] * w[k];
        }
        acc += __shfl_xor(acc, 1);
        acc += __shfl_xor(acc, 2);
        if (kseg == 0) bpart[(size_t)(c0 >> 6) * rows + r0 + rr] = acc;
    }
}

// ---------------- kernel 2: gemmS partials (bf16): Sp[z] = upw3 @ ucb^T, 128x64 tile ----------------
__global__ __launch_bounds__(TPB) void gemmS_mfma(
    const u16* __restrict__ Ah, const u16* __restrict__ Bh,
    u16* __restrict__ Sp, int m, int n, int d, int ksplit) {
    __shared__ u16 sA[128 * 64];
    __shared__ u16 sB[64 * 64];
    int tid = threadIdx.x;
    int lane = tid & 63, wave = tid >> 6;
    int wm = wave >> 1, wn = wave & 1;
    int lrow = lane & 15, g = lane >> 4;
    int i0 = blockIdx.y * 128, j0 = blockIdx.x * 64;
    int kchunk = d / ksplit;
    int kbeg = blockIdx.z * kchunk;
    u16* outS = Sp + (size_t)blockIdx.z * m * n;
    f32x4 acc[4][2];
    #pragma unroll
    for (int a = 0; a < 4; ++a)
        #pragma unroll
        for (int bq = 0; bq < 2; ++bq) acc[a][bq] = (f32x4){0.f, 0.f, 0.f, 0.f};

    for (int k0 = kbeg; k0 < kbeg + kchunk; k0 += 64) {
        #pragma unroll
        for (int it = 0; it < 4; ++it) {
            int id = tid + it * TPB;
            int row = id >> 3, slot = id & 7;
            int boff = (row * 128 + slot * 16) ^ ((row & 7) << 4);
            *(int4*)((char*)sA + boff) = *(const int4*)(Ah + (size_t)(i0 + row) * d + k0 + slot * 8);
        }
        #pragma unroll
        for (int it = 0; it < 2; ++it) {
            int id = tid + it * TPB;
            int row = id >> 3, slot = id & 7;
            int boff = (row * 128 + slot * 16) ^ ((row & 7) << 4);
            *(int4*)((char*)sB + boff) = *(const int4*)(Bh + (size_t)(j0 + row) * d + k0 + slot * 8);
        }
        __syncthreads();
        #pragma unroll
        for (int kk = 0; kk < 2; ++kk) {
            bf16x8 af[4], bf[2];
            #pragma unroll
            for (int mr = 0; mr < 4; ++mr) {
                int row = wm * 64 + mr * 16 + lrow;
                int boff = (row * 128 + kk * 64 + g * 16) ^ ((row & 7) << 4);
                af[mr] = *(const bf16x8*)((const char*)sA + boff);
            }
            #pragma unroll
            for (int nr = 0; nr < 2; ++nr) {
                int row = wn * 32 + nr * 16 + lrow;
                int boff = (row * 128 + kk * 64 + g * 16) ^ ((row & 7) << 4);
                bf[nr] = *(const bf16x8*)((const char*)sB + boff);
            }
            #pragma unroll
            for (int mr = 0; mr < 4; ++mr)
                #pragma unroll
                for (int nr = 0; nr < 2; ++nr)
                    acc[mr][nr] = __builtin_amdgcn_mfma_f32_16x16x32_bf16(af[mr], bf[nr], acc[mr][nr], 0, 0, 0);
        }
        __syncthreads();
    }
    int crow = (lane >> 4) * 4;
    int ccol = lane & 15;
    #pragma unroll
    for (int mr = 0; mr < 4; ++mr)
        #pragma unroll
        for (int nr = 0; nr < 2; ++nr) {
            int jc = j0 + wn * 32 + nr * 16 + ccol;
            #pragma unroll
            for (int jr = 0; jr < 4; ++jr) {
                int i = i0 + wm * 64 + mr * 16 + crow + jr;
                outS[(size_t)i * n + jc] = f2bf(acc[mr][nr][jr]);
            }
        }
}

// ---------------- kernel 3: stats2 = E=exp(sum(Sp)+r+c) -> E bf16 (k-perm), E^T bf16 (i-perm),
//                  rowsum/colsum via atomics. No max-subtraction (|S|<~12, exp safe in f32). ----------------
__global__ __launch_bounds__(TPB) void stats2_kernel(
    const u16* __restrict__ Sp, const float* __restrict__ rpart, const float* __restrict__ cpart,
    u16* __restrict__ E, u16* __restrict__ ET,
    float* __restrict__ rowsum, float* __restrict__ colsum,
    int m, int n, int ksplit) {
    __shared__ float t[64 * 65];
    __shared__ float rl[64], cl[64];
    int tid = threadIdx.x;
    int r0 = blockIdx.y * 64, c0 = blockIdx.x * 64;
    size_t mn = (size_t)m * n;
    int nkc = 32;  // d/64 bias partial chunks
    if (tid < 64) {
        float a = 0.f;
        for (int kc = 0; kc < nkc; ++kc) a += rpart[(size_t)kc * m + r0 + tid];
        rl[tid] = a;
    } else if (tid < 128) {
        int j = tid - 64;
        float a = 0.f;
        for (int kc = 0; kc < nkc; ++kc) a += cpart[(size_t)kc * n + c0 + j];
        cl[j] = a;
    }
    __syncthreads();
    int row = tid >> 2, seg = tid & 3;
    size_t base = (size_t)(r0 + row) * n + c0 + seg * 16;
    float s[16];
    #pragma unroll
    for (int e = 0; e < 16; ++e) s[e] = 0.f;
    #pragma unroll
    for (int z = 0; z < 4; ++z) {
        const u16* sp = Sp + (size_t)z * mn + base;
        int4 q0 = *(const int4*)(sp);
        int4 q1 = *(const int4*)(sp + 8);
        const u16* p0 = (const u16*)&q0;
        const u16* p1 = (const u16*)&q1;
        #pragma unroll
        for (int e = 0; e < 8; ++e) { s[e] += bf2f(p0[e]); s[8 + e] += bf2f(p1[e]); }
    }
    float rv = rl[row];
    float racc = 0.f;
    u16 h[16];
    #pragma unroll
    for (int e = 0; e < 16; ++e) {
        int col = seg * 16 + e;
        float Sv = s[e] + rv + cl[col];
        float ex = __expf(Sv);
        h[e] = f2bf(ex);
        float er = bf2f(h[e]);
        racc += er;
        t[col * 65 + row] = er;
    }
    // E row-major, k-perm on col
    #pragma unroll
    for (int g = 0; g < 4; ++g) {
        int C = c0 + seg * 16 + g * 4;
        int p = (C & ~31) + pos32(C & 31);
        *(u16x4*)(E + (size_t)(r0 + row) * n + p) = *(u16x4*)&h[g * 4];
    }
    racc += __shfl_xor(racc, 1);
    racc += __shfl_xor(racc, 2);
    if (seg == 0) unsafeAtomicAdd(rowsum + r0 + row, racc);
    __syncthreads();
    // col sums + E^T (i-perm)
    int col = tid >> 2, rseg = tid & 3;
    float cacc = 0.f;
    u16 hv[16];
    #pragma unroll
    for (int rr = 0; rr < 16; ++rr) {
        float val = t[col * 65 + rseg * 16 + rr];
        cacc += val;
        hv[rr] = f2bf(val);
    }
    cacc += __shfl_xor(cacc, 1);
    cacc += __shfl_xor(cacc, 2);
    if (rseg == 0) unsafeAtomicAdd(colsum + c0 + col, cacc);
    #pragma unroll
    for (int g = 0; g < 4; ++g) {
        int I = rseg * 16 + g * 4;
        int p = (I & ~31) + pos32(I & 31);
        *(u16x4*)(ET + (size_t)(c0 + col) * m + r0 + p) = *(u16x4*)&hv[g * 4];
    }
}

// ---------------- kernel 4: attn = two bf16 GEMMs with post-normalization epilogue ----------------
__global__ __launch_bounds__(TPB) void attn_mfma(
    const u16* __restrict__ E, const u16* __restrict__ ET,
    const u16* __restrict__ ucT, const u16* __restrict__ upT,
    const float* __restrict__ rowsum, const float* __restrict__ colsum,
    u16* __restrict__ aalpha, u16* __restrict__ abeta,
    int m, int n, int d) {
    __shared__ u16 sA[128 * 64];
    __shared__ u16 sB[64 * 64];
    int tid = threadIdx.x;
    int lane = tid & 63, wave = tid >> 6;
    int wm = wave >> 1, wn = wave & 1;
    int lrow = lane & 15, g = lane >> 4;
    int i0 = blockIdx.y * 128, kc0 = blockIdx.x * 64;
    const u16* A; const u16* B; u16* outp; const float* sums; int kT;
    if (blockIdx.z == 0) { A = E;  B = ucT; outp = aalpha; sums = rowsum; kT = n; }
    else                 { A = ET; B = upT; outp = abeta;  sums = colsum; kT = m; }
    f32x4 acc[4][2];
    #pragma unroll
    for (int a = 0; a < 4; ++a)
        #pragma unroll
        for (int bq = 0; bq < 2; ++bq) acc[a][bq] = (f32x4){0.f, 0.f, 0.f, 0.f};

    for (int k0 = 0; k0 < kT; k0 += 64) {
        #pragma unroll
        for (int it = 0; it < 4; ++it) {
            int id = tid + it * TPB;
            int row = id >> 3, slot = id & 7;
            int boff = (row * 128 + slot * 16) ^ ((row & 7) << 4);
            *(int4*)((char*)sA + boff) = *(const int4*)(A + (size_t)(i0 + row) * kT + k0 + slot * 8);
        }
        #pragma unroll
        for (int it = 0; it < 2; ++it) {
            int id = tid + it * TPB;
            int row = id >> 3, slot = id & 7;
            int boff = (row * 128 + slot * 16) ^ ((row & 7) << 4);
            *(int4*)((char*)sB + boff) = *(const int4*)(B + (size_t)(kc0 + row) * kT + k0 + slot * 8);
        }
        __syncthreads();
        #pragma unroll
        for (int kk = 0; kk < 2; ++kk) {
            bf16x8 af[4], bf[2];
            #pragma unroll
            for (int mr = 0; mr < 4; ++mr) {
                int row = wm * 64 + mr * 16 + lrow;
                int boff = (row * 128 + kk * 64 + g * 16) ^ ((row & 7) << 4);
                af[mr] = *(const bf16x8*)((const char*)sA + boff);
            }
            #pragma unroll
            for (int nr = 0; nr < 2; ++nr) {
                int row = wn * 32 + nr * 16 + lrow;
                int boff = (row * 128 + kk * 64 + g * 16) ^ ((row & 7) << 4);
                bf[nr] = *(const bf16x8*)((const char*)sB + boff);
            }
            #pragma unroll
            for (int mr = 0; mr < 4; ++mr)
                #pragma unroll
                for (int nr = 0; nr < 2; ++nr)
                    acc[mr][nr] = __builtin_amdgcn_mfma_f32_16x16x32_bf16(af[mr], bf[nr], acc[mr][nr], 0, 0, 0);
        }
        __syncthreads();
    }
    int crow = (lane >> 4) * 4;
    int ccol = lane & 15;
    #pragma unroll
    for (int mr = 0; mr < 4; ++mr)
        #pragma unroll
        for (int jr = 0; jr < 4; ++jr) {
            int i = i0 + wm * 64 + mr * 16 + crow + jr;
            float inv = 1.f / sums[i];
            #pragma unroll
            for (int nr = 0; nr < 2; ++nr) {
                int kc = kc0 + wn * 32 + nr * 16 + ccol;
                outp[(size_t)i * d + kc] = f2bf(acc[mr][nr][jr] * inv);
            }
        }
}

// ---------------- kernel 5: fused final dot, stage 1 ----------------
__global__ __launch_bounds__(TPB) void final_stage1(
    const float* __restrict__ u_p, const float* __restrict__ u_c,
    const u16* __restrict__ aalpha, const u16* __restrict__ abeta,
    const float* __restrict__ W, float* __restrict__ partials, int n, int d) {
    size_t total = (size_t)n * d / 4;
    float acc = 0.f;
    for (size_t q = (size_t)blockIdx.x * TPB + threadIdx.x; q < total;
         q += (size_t)gridDim.x * TPB) {
        size_t e = q * 4;
        int i = (int)(e / d);
        int k = (int)(e % d);
        size_t base = (size_t)i * d + k;
        float4 up = *(const float4*)(u_p + base);
        float4 uc = *(const float4*)(u_c + base);
        u16x4 aah = *(const u16x4*)(aalpha + base);
        u16x4 abh = *(const u16x4*)(abeta + base);
        float4 aa = {bf2f(aah[0]), bf2f(aah[1]), bf2f(aah[2]), bf2f(aah[3])};
        float4 ab = {bf2f(abh[0]), bf2f(abh[1]), bf2f(abh[2]), bf2f(abh[3])};
        const float* wr = W + (size_t)i * 4 * d;
        float4 w0 = *(const float4*)(wr + k);
        float4 w1 = *(const float4*)(wr + d + k);
        float4 w2 = *(const float4*)(wr + 2 * d + k);
        float4 w3 = *(const float4*)(wr + 3 * d + k);
        acc += up.x * w0.x + aa.x * (w1.x + up.x * w2.x) + uc.x * ab.x * w3.x;
        acc += up.y * w0.y + aa.y * (w1.y + up.y * w2.y) + uc.y * ab.y * w3.y;
        acc += up.z * w0.z + aa.z * (w1.z + up.z * w2.z) + uc.z * ab.z * w3.z;
        acc += up.w * w0.w + aa.w * (w1.w + up.w * w2.w) + uc.w * ab.w * w3.w;
    }
    __shared__ float red[TPB];
    red[threadIdx.x] = acc;
    __syncthreads();
    for (int s = TPB / 2; s > 0; s >>= 1) {
        if (threadIdx.x < s) red[threadIdx.x] += red[threadIdx.x + s];
        __syncthreads();
    }
    if (threadIdx.x == 0) partials[blockIdx.x] = red[0];
}

// ---------------- kernel 6: stage 2 ----------------
__global__ __launch_bounds__(TPB) void final_stage2(
    const float* __restrict__ partials, int np, const float* __restrict__ bias,
    float* __restrict__ out) {
    double acc = 0.0;
    for (int t = threadIdx.x; t < np; t += TPB) acc += (double)partials[t];
    __shared__ double red[TPB];
    red[threadIdx.x] = acc;
    __syncthreads();
    for (int s = TPB / 2; s > 0; s >>= 1) {
        if (threadIdx.x < s) red[threadIdx.x] += red[threadIdx.x + s];
        __syncthreads();
    }
    if (threadIdx.x == 0) {
        double v = red[0] + (double)bias[0];
        out[0] = (float)(v > 0.0 ? v : 0.0);
    }
}

extern "C" void kernel_launch(void* const* d_in, const int* in_sizes, int n_in,
                              void* d_out, int out_size, void* d_ws, size_t ws_size,
                              hipStream_t stream) {
    const float* u_p = (const float*)d_in[0];
    const float* u_c = (const float*)d_in[1];
    const float* w_a = (const float*)d_in[2];
    const float* ffn_w = (const float*)d_in[3];
    const float* ffn_b = (const float*)d_in[4];
    float* out = (float*)d_out;

    int d = in_sizes[2] / 3;   // 2048
    int m = in_sizes[0] / d;   // 1024
    int n = in_sizes[1] / d;   // 1024  (assumes m == n)
    const int NBLK_FINAL = 2048;
    const int KSPLIT = 4;
    int nkc = d / 64;          // 32 bias-partial chunks

    size_t md = (size_t)m * d, nd = (size_t)n * d, mn = (size_t)m * n;

    float* ws = (float*)d_ws;
    float* rowsum = ws;                      // m   } zbuf (contiguous, zeroed in prep)
    float* colsum = rowsum + m;              // n   }
    float* rpart = colsum + n;               // nkc*m
    float* cpart = rpart + (size_t)nkc * m;  // nkc*n
    float* partials = cpart + (size_t)nkc * n;  // NBLK_FINAL
    u16* Sp = (u16*)(partials + NBLK_FINAL); // KSPLIT*mn u16
    u16* E = Sp + (size_t)KSPLIT * mn;       // mn
    u16* ET = E + mn;                        // mn
    u16* aalpha = ET + mn;                   // md
    u16* abeta = aalpha + md;                // nd
    u16* upw3 = abeta + nd;                  // md
    u16* ucb = upw3 + md;                    // nd
    u16* ucT = ucb + nd;                     // nd
    u16* upT = ucT + nd;                     // md

    int nTc = (d / 64) * (n / 64);   // 512
    int nTp = (d / 64) * (m / 64);   // 512
    prep_kernel<<<nTc + nTp, TPB, 0, stream>>>(
        u_p, u_c, w_a, upw3, ucb, ucT, upT, rpart, cpart, rowsum, m, n, d, nTc);

    dim3 gS(n / 64, m / 128, KSPLIT);
    gemmS_mfma<<<gS, TPB, 0, stream>>>(upw3, ucb, Sp, m, n, d, KSPLIT);

    dim3 gT(n / 64, m / 64);
    stats2_kernel<<<gT, TPB, 0, stream>>>(Sp, rpart, cpart, E, ET, rowsum, colsum, m, n, KSPLIT);

    dim3 gA(d / 64, m / 128, 2);
    attn_mfma<<<gA, TPB, 0, stream>>>(E, ET, ucT, upT, rowsum, colsum, aalpha, abeta, m, n, d);

    final_stage1<<<NBLK_FINAL, TPB, 0, stream>>>(u_p, u_c, aalpha, abeta, ffn_w,
                                                 partials, n, d);
    final_stage2<<<1, TPB, 0, stream>>>(partials, NBLK_FINAL, ffn_b, out);

    (void)out_size; (void)ws_size; (void)n_in;
}

// Round 11
// 55.275 us; speedup vs baseline: 3.3527x; 1.1815x over previous
//
#include <hip/hip_runtime.h>
#include <math.h>

#define TPB 256

typedef unsigned short u16;
typedef short bf16x8 __attribute__((ext_vector_type(8)));
typedef unsigned short u16x4 __attribute__((ext_vector_type(4)));
typedef float f32x4 __attribute__((ext_vector_type(4)));

__device__ __forceinline__ u16 f2bf(float x) {
    unsigned u = __float_as_uint(x);
    unsigned r = u + 0x7fffu + ((u >> 16) & 1u);
    return (u16)(r >> 16);
}
__device__ __forceinline__ float bf2f(u16 h) {
    return __uint_as_float(((unsigned)h) << 16);
}
// k-permutation within 32-chunk (half-split fragment layout); applied to BOTH
// operands of every GEMM -> dot over k is permutation-invariant.
__device__ __forceinline__ int pos32(int kk) {
    return ((kk >> 2) & 3) * 8 + (kk >> 4) * 4 + (kk & 3);
}
__device__ __forceinline__ int ipos32(int p5) {
    return 16 * ((p5 >> 2) & 1) + 4 * (p5 >> 3) + (p5 & 3);
}

// Tile-blocked-swizzled (TBS) storage: matrix[R][K] bf16 stored as 64x64 tiles,
// tile (tr, tk) = 8192 bytes at ((tr*(K/64)+tk)<<13). Within tile, element
// (row, p) (p = permuted k) at byte row*128 + (((p>>3)<<4) ^ ((row&7)<<4)) + (p&7)*2.
// This equals the LDS image the GEMMs read -> staging is a byte-linear copy.

#if defined(__has_builtin)
#if __has_builtin(__builtin_amdgcn_global_load_lds)
#define HAS_GLL 1
#endif
#endif
#ifndef HAS_GLL
#define HAS_GLL 0
#endif

__device__ __forceinline__ void gl16(const char* g, char* l) {
#if HAS_GLL
    __builtin_amdgcn_global_load_lds(
        (const __attribute__((address_space(1))) void*)(unsigned long long)g,
        (__attribute__((address_space(3))) void*)(unsigned int)(unsigned long long)l,
        16, 0, 0);
#else
    *(int4*)l = *(const int4*)g;
#endif
}

// ---------------- kernel 1: prep = transpose+convert (TBS) + bias partials + term1 ----------------
__global__ __launch_bounds__(TPB) void prep_kernel(
    const float* __restrict__ up, const float* __restrict__ uc,
    const float* __restrict__ wa, const float* __restrict__ W,
    u16* __restrict__ upw3, u16* __restrict__ ucb,
    u16* __restrict__ ucT, u16* __restrict__ upT,
    float* __restrict__ rpart, float* __restrict__ cpart,
    float* __restrict__ zbuf, float* __restrict__ fpart,
    int m, int n, int d, int nTc) {
    __shared__ float t[64 * 65];
    __shared__ float wred[4];
    int b = blockIdx.x, tid = threadIdx.x;
    if (b < 8) {  // zero rowsum/colsum (consumers in later kernels)
        int idx = b * TPB + tid;
        if (idx < 2 * m) zbuf[idx] = 0.f;
    }
    const float* src; u16* dstT; u16* dstR; float* bpart; int rows; int tt; int isUp;
    if (b < nTc) { src = uc; dstT = ucT; dstR = ucb;  bpart = cpart; rows = n; tt = b;       isUp = 0; }
    else         { src = up; dstT = upT; dstR = upw3; bpart = rpart; rows = m; tt = b - nTc; isUp = 1; }
    int ntx = d / 64;
    int c0 = (tt % ntx) * 64;   // k-range
    int r0 = (tt / ntx) * 64;   // sample-row range

    // load tile into LDS transposed: t[k_local][row_local]
    #pragma unroll
    for (int it = 0; it < 4; ++it) {
        int rr = (tid >> 4) + it * 16;
        int cc = (tid & 15) * 4;
        float4 v = *(const float4*)(src + (size_t)(r0 + rr) * d + c0 + cc);
        t[(cc + 0) * 65 + rr] = v.x;
        t[(cc + 1) * 65 + rr] = v.y;
        t[(cc + 2) * 65 + rr] = v.z;
        t[(cc + 3) * 65 + rr] = v.w;
    }
    __syncthreads();
    // phase 2: transposed TBS output dstT (rows of dstT = k; cols = sample, permuted)
    {
        char* tbase = (char*)dstT + (((size_t)(c0 >> 6) * (rows >> 6) + (r0 >> 6)) << 13);
        #pragma unroll
        for (int it = 0; it < 2; ++it) {
            int id = tid + it * TPB;
            int kc = id >> 3;
            int s = id & 7;
            u16 outv[8];
            #pragma unroll
            for (int e = 0; e < 8; ++e) {
                int p = s * 8 + e;
                int jloc = 32 * (p >> 5) + ipos32(p & 31);
                outv[e] = f2bf(t[kc * 65 + jloc]);
            }
            char* pp = tbase + kc * 128 + ((s * 16) ^ ((kc & 7) << 4));
            *(u16x4*)pp = *(u16x4*)&outv[0];
            *(u16x4*)(pp + 8) = *(u16x4*)&outv[4];
        }
    }
    // phase 3: row-major TBS output dstR (k permuted), *w3 for up
    {
        char* rbase = (char*)dstR + (((size_t)(r0 >> 6) * (d >> 6) + (c0 >> 6)) << 13);
        int rr = tid >> 2;
        int cbase = (tid & 3) * 16;
        #pragma unroll
        for (int grp = 0; grp < 4; ++grp) {
            int kl = cbase + grp * 4;
            u16x4 o;
            #pragma unroll
            for (int e = 0; e < 4; ++e) {
                float val = t[(kl + e) * 65 + rr];
                if (isUp) val *= wa[2 * d + c0 + kl + e];
                o[e] = f2bf(val);
            }
            int pl = (kl & ~31) + pos32(kl & 31);
            *(u16x4*)(rbase + rr * 128 + (((pl >> 3) << 4) ^ ((rr & 7) << 4)) + (pl & 7) * 2) = o;
        }
    }
    // phase 4: bias partials bpart[kchunk][row] = sum_k tile[row,k]*w{1,2}[k]
    {
        int rr = tid >> 2;
        int kseg = tid & 3;
        const float* w = wa + (isUp ? 0 : d) + c0;
        float acc = 0.f;
        #pragma unroll
        for (int kk = 0; kk < 16; ++kk) {
            int k = kseg * 16 + kk;
            acc += t[k * 65 + rr] * w[k];
        }
        acc += __shfl_xor(acc, 1);
        acc += __shfl_xor(acc, 2);
        if (kseg == 0) bpart[(size_t)(c0 >> 6) * rows + r0 + rr] = acc;
    }
    // phase 5 (up tiles only): term1 partial = sum tile[rr,k]*W0[r0+rr, c0+k]
    if (isUp) {
        int rr = tid >> 2;
        int kseg = tid & 3;
        const float* w0r = W + (size_t)(r0 + rr) * 4 * d + c0 + kseg * 16;
        float acc = 0.f;
        #pragma unroll
        for (int kk = 0; kk < 16; ++kk) acc += t[(kseg * 16 + kk) * 65 + rr] * w0r[kk];
        #pragma unroll
        for (int off = 32; off > 0; off >>= 1) acc += __shfl_down(acc, off);
        if ((tid & 63) == 0) wred[tid >> 6] = acc;
        __syncthreads();
        if (tid == 0) fpart[tt] = wred[0] + wred[1] + wred[2] + wred[3];
    }
}

// ---------------- kernel 2: gemmS partials (bf16): Sp[z] = upw3 @ ucb^T, 128x64 tile, gload staging ----------------
__global__ __launch_bounds__(TPB) void gemmS_mfma(
    const u16* __restrict__ Ah, const u16* __restrict__ Bh,
    u16* __restrict__ Sp, int m, int n, int d, int ksplit) {
    __shared__ u16 sA[128 * 64];
    __shared__ u16 sB[64 * 64];
    int tid = threadIdx.x;
    int lane = tid & 63, wave = tid >> 6;
    int wm = wave >> 1, wn = wave & 1;
    int lrow = lane & 15, g = lane >> 4;
    int by = blockIdx.y, bx = blockIdx.x;
    int i0 = by * 128, j0 = bx * 64;
    int ntk = d >> 6;
    int ktiles = ntk / ksplit;
    int tk0 = blockIdx.z * ktiles;
    u16* outS = Sp + (size_t)blockIdx.z * m * n;
    f32x4 acc[4][2];
    #pragma unroll
    for (int a = 0; a < 4; ++a)
        #pragma unroll
        for (int bq = 0; bq < 2; ++bq) acc[a][bq] = (f32x4){0.f, 0.f, 0.f, 0.f};

    int o = tid * 16;
    for (int tk = tk0; tk < tk0 + ktiles; ++tk) {
        const char* gA0 = (const char*)Ah + (((size_t)(2 * by) * ntk + tk) << 13);
        const char* gA1 = gA0 + ((size_t)ntk << 13);
        const char* gB = (const char*)Bh + (((size_t)bx * ntk + tk) << 13);
        gl16(gA0 + o, (char*)sA + o);
        gl16(gA0 + 4096 + o, (char*)sA + 4096 + o);
        gl16(gA1 + o, (char*)sA + 8192 + o);
        gl16(gA1 + 4096 + o, (char*)sA + 12288 + o);
        gl16(gB + o, (char*)sB + o);
        gl16(gB + 4096 + o, (char*)sB + 4096 + o);
        __syncthreads();
        #pragma unroll
        for (int kk = 0; kk < 2; ++kk) {
            bf16x8 af[4], bf[2];
            #pragma unroll
            for (int mr = 0; mr < 4; ++mr) {
                int row = wm * 64 + mr * 16 + lrow;
                int boff = (row * 128 + kk * 64 + g * 16) ^ ((row & 7) << 4);
                af[mr] = *(const bf16x8*)((const char*)sA + boff);
            }
            #pragma unroll
            for (int nr = 0; nr < 2; ++nr) {
                int row = wn * 32 + nr * 16 + lrow;
                int boff = (row * 128 + kk * 64 + g * 16) ^ ((row & 7) << 4);
                bf[nr] = *(const bf16x8*)((const char*)sB + boff);
            }
            #pragma unroll
            for (int mr = 0; mr < 4; ++mr)
                #pragma unroll
                for (int nr = 0; nr < 2; ++nr)
                    acc[mr][nr] = __builtin_amdgcn_mfma_f32_16x16x32_bf16(af[mr], bf[nr], acc[mr][nr], 0, 0, 0);
        }
        __syncthreads();
    }
    int crow = (lane >> 4) * 4;
    int ccol = lane & 15;
    #pragma unroll
    for (int mr = 0; mr < 4; ++mr)
        #pragma unroll
        for (int nr = 0; nr < 2; ++nr) {
            int jc = j0 + wn * 32 + nr * 16 + ccol;
            #pragma unroll
            for (int jr = 0; jr < 4; ++jr) {
                int i = i0 + wm * 64 + mr * 16 + crow + jr;
                outS[(size_t)i * n + jc] = f2bf(acc[mr][nr][jr]);
            }
        }
}

// ---------------- kernel 3: stats2 = E=exp(sum(Sp)+r+c) -> E,ET in TBS bf16; rowsum/colsum atomics ----------------
__global__ __launch_bounds__(TPB) void stats2_kernel(
    const u16* __restrict__ Sp, const float* __restrict__ rpart, const float* __restrict__ cpart,
    u16* __restrict__ E, u16* __restrict__ ET,
    float* __restrict__ rowsum, float* __restrict__ colsum,
    int m, int n) {
    __shared__ float t[64 * 65];
    __shared__ float rl[64], cl[64];
    int tid = threadIdx.x;
    int r0 = blockIdx.y * 64, c0 = blockIdx.x * 64;
    size_t mn = (size_t)m * n;
    int nkc = 32;  // d/64 bias partial chunks
    if (tid < 64) {
        float a = 0.f;
        for (int kc = 0; kc < nkc; ++kc) a += rpart[(size_t)kc * m + r0 + tid];
        rl[tid] = a;
    } else if (tid < 128) {
        int j = tid - 64;
        float a = 0.f;
        for (int kc = 0; kc < nkc; ++kc) a += cpart[(size_t)kc * n + c0 + j];
        cl[j] = a;
    }
    __syncthreads();
    int row = tid >> 2, seg = tid & 3;
    size_t base = (size_t)(r0 + row) * n + c0 + seg * 16;
    float s[16];
    #pragma unroll
    for (int e = 0; e < 16; ++e) s[e] = 0.f;
    #pragma unroll
    for (int z = 0; z < 4; ++z) {
        const u16* sp = Sp + (size_t)z * mn + base;
        int4 q0 = *(const int4*)(sp);
        int4 q1 = *(const int4*)(sp + 8);
        const u16* p0 = (const u16*)&q0;
        const u16* p1 = (const u16*)&q1;
        #pragma unroll
        for (int e = 0; e < 8; ++e) { s[e] += bf2f(p0[e]); s[8 + e] += bf2f(p1[e]); }
    }
    float rv = rl[row];
    float racc = 0.f;
    u16 h[16];
    #pragma unroll
    for (int e = 0; e < 16; ++e) {
        int col = seg * 16 + e;
        float ex = __expf(s[e] + rv + cl[col]);
        h[e] = f2bf(ex);
        float er = bf2f(h[e]);
        racc += er;
        t[col * 65 + row] = er;
    }
    // E (TBS): rows=i, cols=j permuted
    char* Ebase = (char*)E + (((size_t)(r0 >> 6) * (n >> 6) + (c0 >> 6)) << 13);
    #pragma unroll
    for (int g = 0; g < 4; ++g) {
        int cl4 = seg * 16 + g * 4;
        int pl = (cl4 & ~31) + pos32(cl4 & 31);
        *(u16x4*)(Ebase + row * 128 + (((pl >> 3) << 4) ^ ((row & 7) << 4)) + (pl & 7) * 2) = *(u16x4*)&h[g * 4];
    }
    racc += __shfl_xor(racc, 1);
    racc += __shfl_xor(racc, 2);
    if (seg == 0) unsafeAtomicAdd(rowsum + r0 + row, racc);
    __syncthreads();
    // ET (TBS): rows=j, cols=i permuted; + colsum
    int col = tid >> 2, rseg = tid & 3;
    float cacc = 0.f;
    u16 hv[16];
    #pragma unroll
    for (int rr = 0; rr < 16; ++rr) {
        float val = t[col * 65 + rseg * 16 + rr];
        cacc += val;
        hv[rr] = f2bf(val);
    }
    cacc += __shfl_xor(cacc, 1);
    cacc += __shfl_xor(cacc, 2);
    if (rseg == 0) unsafeAtomicAdd(colsum + c0 + col, cacc);
    char* ETbase = (char*)ET + (((size_t)(c0 >> 6) * (m >> 6) + (r0 >> 6)) << 13);
    #pragma unroll
    for (int g = 0; g < 4; ++g) {
        int il = rseg * 16 + g * 4;
        int pl = (il & ~31) + pos32(il & 31);
        *(u16x4*)(ETbase + col * 128 + (((pl >> 3) << 4) ^ ((col & 7) << 4)) + (pl & 7) * 2) = *(u16x4*)&hv[g * 4];
    }
}

// ---------------- kernel 4: attn = two bf16 GEMMs, gload staging, fused FFN-dot epilogue ----------------
__global__ __launch_bounds__(TPB) void attn_mfma(
    const u16* __restrict__ E, const u16* __restrict__ ET,
    const u16* __restrict__ ucT, const u16* __restrict__ upT,
    const float* __restrict__ up, const float* __restrict__ uc,
    const float* __restrict__ W,
    const float* __restrict__ rowsum, const float* __restrict__ colsum,
    float* __restrict__ fpart2, int m, int n, int d) {
    __shared__ u16 sA[128 * 64];
    __shared__ u16 sB[64 * 64];
    __shared__ float red[TPB];
    int tid = threadIdx.x;
    int lane = tid & 63, wave = tid >> 6;
    int wm = wave >> 1, wn = wave & 1;
    int lrow = lane & 15, g = lane >> 4;
    int by = blockIdx.y, bx = blockIdx.x, bz = blockIdx.z;
    int i0 = by * 128, kc0 = bx * 64;
    const u16* A; const u16* B; const float* sums; int kT;
    if (bz == 0) { A = E;  B = ucT; sums = rowsum; kT = n; }
    else         { A = ET; B = upT; sums = colsum; kT = m; }
    int ntk = kT >> 6;
    f32x4 acc[4][2];
    #pragma unroll
    for (int a = 0; a < 4; ++a)
        #pragma unroll
        for (int bq = 0; bq < 2; ++bq) acc[a][bq] = (f32x4){0.f, 0.f, 0.f, 0.f};

    int o = tid * 16;
    for (int tj = 0; tj < ntk; ++tj) {
        const char* gA0 = (const char*)A + (((size_t)(2 * by) * ntk + tj) << 13);
        const char* gA1 = gA0 + ((size_t)ntk << 13);
        const char* gB = (const char*)B + (((size_t)bx * ntk + tj) << 13);
        gl16(gA0 + o, (char*)sA + o);
        gl16(gA0 + 4096 + o, (char*)sA + 4096 + o);
        gl16(gA1 + o, (char*)sA + 8192 + o);
        gl16(gA1 + 4096 + o, (char*)sA + 12288 + o);
        gl16(gB + o, (char*)sB + o);
        gl16(gB + 4096 + o, (char*)sB + 4096 + o);
        __syncthreads();
        #pragma unroll
        for (int kk = 0; kk < 2; ++kk) {
            bf16x8 af[4], bf[2];
            #pragma unroll
            for (int mr = 0; mr < 4; ++mr) {
                int row = wm * 64 + mr * 16 + lrow;
                int boff = (row * 128 + kk * 64 + g * 16) ^ ((row & 7) << 4);
                af[mr] = *(const bf16x8*)((const char*)sA + boff);
            }
            #pragma unroll
            for (int nr = 0; nr < 2; ++nr) {
                int row = wn * 32 + nr * 16 + lrow;
                int boff = (row * 128 + kk * 64 + g * 16) ^ ((row & 7) << 4);
                bf[nr] = *(const bf16x8*)((const char*)sB + boff);
            }
            #pragma unroll
            for (int mr = 0; mr < 4; ++mr)
                #pragma unroll
                for (int nr = 0; nr < 2; ++nr)
                    acc[mr][nr] = __builtin_amdgcn_mfma_f32_16x16x32_bf16(af[mr], bf[nr], acc[mr][nr], 0, 0, 0);
        }
        __syncthreads();
    }
    int crow = (lane >> 4) * 4;
    int ccol = lane & 15;
    float tsum = 0.f;
    if (bz == 0) {
        // term2: aalpha[i,kc] * (W1[i,kc] + up[i,kc]*W2[i,kc])
        #pragma unroll
        for (int mr = 0; mr < 4; ++mr)
            #pragma unroll
            for (int jr = 0; jr < 4; ++jr) {
                int i = i0 + wm * 64 + mr * 16 + crow + jr;
                float inv = 1.f / sums[i];
                const float* wr = W + (size_t)i * 4 * d;
                const float* upr = up + (size_t)i * d;
                #pragma unroll
                for (int nr = 0; nr < 2; ++nr) {
                    int kc = kc0 + wn * 32 + nr * 16 + ccol;
                    float aa = acc[mr][nr][jr] * inv;
                    tsum += aa * (wr[d + kc] + upr[kc] * wr[2 * d + kc]);
                }
            }
    } else {
        // term3: abeta[j,kc] * uc[j,kc] * W3[j,kc]
        #pragma unroll
        for (int mr = 0; mr < 4; ++mr)
            #pragma unroll
            for (int jr = 0; jr < 4; ++jr) {
                int j = i0 + wm * 64 + mr * 16 + crow + jr;
                float inv = 1.f / sums[j];
                const float* wr = W + (size_t)j * 4 * d;
                const float* ucr = uc + (size_t)j * d;
                #pragma unroll
                for (int nr = 0; nr < 2; ++nr) {
                    int kc = kc0 + wn * 32 + nr * 16 + ccol;
                    float ab = acc[mr][nr][jr] * inv;
                    tsum += ab * ucr[kc] * wr[3 * d + kc];
                }
            }
    }
    red[tid] = tsum;
    __syncthreads();
    for (int s = TPB / 2; s > 0; s >>= 1) {
        if (tid < s) red[tid] += red[tid + s];
        __syncthreads();
    }
    if (tid == 0)
        fpart2[(size_t)bz * gridDim.x * gridDim.y + (size_t)by * gridDim.x + bx] = red[0];
}

// ---------------- kernel 5: final = relu(sum(fparts) + bias) ----------------
__global__ __launch_bounds__(TPB) void final_out(
    const float* __restrict__ fparts, int cnt, const float* __restrict__ bias,
    float* __restrict__ out) {
    __shared__ double red[TPB];
    double a = 0.0;
    for (int i = threadIdx.x; i < cnt; i += TPB) a += (double)fparts[i];
    red[threadIdx.x] = a;
    __syncthreads();
    for (int s = TPB / 2; s > 0; s >>= 1) {
        if (threadIdx.x < s) red[threadIdx.x] += red[threadIdx.x + s];
        __syncthreads();
    }
    if (threadIdx.x == 0) {
        double v = red[0] + (double)bias[0];
        out[0] = (float)(v > 0.0 ? v : 0.0);
    }
}

extern "C" void kernel_launch(void* const* d_in, const int* in_sizes, int n_in,
                              void* d_out, int out_size, void* d_ws, size_t ws_size,
                              hipStream_t stream) {
    const float* u_p = (const float*)d_in[0];
    const float* u_c = (const float*)d_in[1];
    const float* w_a = (const float*)d_in[2];
    const float* ffn_w = (const float*)d_in[3];
    const float* ffn_b = (const float*)d_in[4];
    float* out = (float*)d_out;

    int d = in_sizes[2] / 3;   // 2048
    int m = in_sizes[0] / d;   // 1024
    int n = in_sizes[1] / d;   // 1024  (assumes m == n)
    const int KSPLIT = 4;
    int nkc = d / 64;          // 32

    size_t md = (size_t)m * d, nd = (size_t)n * d, mn = (size_t)m * n;
    int nTc = (d / 64) * (n / 64);   // 512
    int nTp = (d / 64) * (m / 64);   // 512
    int nF2 = 2 * (d / 64) * (m / 128);  // 512

    float* ws = (float*)d_ws;
    float* rowsum = ws;                       // m  } zbuf (zeroed in prep)
    float* colsum = rowsum + m;               // n  }
    float* rpart = colsum + n;                // nkc*m
    float* cpart = rpart + (size_t)nkc * m;   // nkc*n
    float* fpart = cpart + (size_t)nkc * n;   // nTp (term1, written by prep)
    float* fpart2 = fpart + nTp;              // nF2 (terms 2,3, written by attn)
    u16* Sp = (u16*)(fpart2 + nF2);           // KSPLIT*mn
    u16* E = Sp + (size_t)KSPLIT * mn;        // mn (TBS)
    u16* ET = E + mn;                         // mn (TBS)
    u16* upw3 = ET + mn;                      // md (TBS)
    u16* ucb = upw3 + md;                     // nd (TBS)
    u16* ucT = ucb + nd;                      // nd (TBS)
    u16* upT = ucT + nd;                      // md (TBS)

    prep_kernel<<<nTc + nTp, TPB, 0, stream>>>(
        u_p, u_c, w_a, ffn_w, upw3, ucb, ucT, upT, rpart, cpart, rowsum, fpart,
        m, n, d, nTc);

    dim3 gS(n / 64, m / 128, KSPLIT);
    gemmS_mfma<<<gS, TPB, 0, stream>>>(upw3, ucb, Sp, m, n, d, KSPLIT);

    dim3 gT(n / 64, m / 64);
    stats2_kernel<<<gT, TPB, 0, stream>>>(Sp, rpart, cpart, E, ET, rowsum, colsum, m, n);

    dim3 gA(d / 64, m / 128, 2);
    attn_mfma<<<gA, TPB, 0, stream>>>(E, ET, ucT, upT, u_p, u_c, ffn_w,
                                      rowsum, colsum, fpart2, m, n, d);

    final_out<<<1, TPB, 0, stream>>>(fpart, nTp + nF2, ffn_b, out);

    (void)out_size; (void)ws_size; (void)n_in;
}